// Round 1
// baseline (1356.530 us; speedup 1.0000x reference)
//
#include <hip/hip_runtime.h>

#define N_NODES 100000
#define N_EDGES 3200000
#define IN_C 1433
#define DIM 32
#define HEADS 8
#define OUT_C 4
#define NUM_CLASS 7

// ---------------------------------------------------------------------------
// proj: h[n][c] = sum_k x[n][k] * w[k][c] + b[c]
// tile: 128 nodes x 32 cols, BK=64. 256 threads, 4x4 register tile.
// ---------------------------------------------------------------------------
#define PBM 128
#define PBK 64
#define XS_STRIDE 132   // 128 + 4 pad: conflict-light writes, aligned b128 reads

__global__ __launch_bounds__(256) void proj_kernel(
    const float* __restrict__ x, const float* __restrict__ w,
    const float* __restrict__ b, float* __restrict__ h) {
  __shared__ float xs[PBK * XS_STRIDE];   // [kk][node], padded
  __shared__ float ws[PBK * DIM];         // [kk][col]
  const int t = threadIdx.x;
  const int tcol = t & 7;        // col group: cols tcol*4 .. +3
  const int trow = t >> 3;       // node group: nodes trow*4 .. +3
  const int nodeBase = blockIdx.x * PBM;

  float acc[4][4] = {};

  for (int k0 = 0; k0 < IN_C; k0 += PBK) {
    __syncthreads();
    // stage x: each pass, wave (t>>6) reads 64 consecutive k of one node
    const int kk = t & 63;
    const int gk = k0 + kk;
    #pragma unroll 4
    for (int p = 0; p < 32; ++p) {
      const int ln = p * 4 + (t >> 6);
      const int gn = nodeBase + ln;
      float v = 0.f;
      if (gn < N_NODES && gk < IN_C) v = x[(size_t)gn * IN_C + gk];
      xs[kk * XS_STRIDE + ln] = v;
    }
    // stage w: 2 passes of float4 (w rows are 32 floats, 16B aligned)
    {
      int wkk = t >> 3;
      const int wcol = (t & 7) * 4;
      #pragma unroll
      for (int p = 0; p < 2; ++p, wkk += 32) {
        const int gwk = k0 + wkk;
        float4 v = make_float4(0.f, 0.f, 0.f, 0.f);
        if (gwk < IN_C) v = *(const float4*)(w + (size_t)gwk * DIM + wcol);
        *(float4*)(ws + wkk * DIM + wcol) = v;
      }
    }
    __syncthreads();

    #pragma unroll 8
    for (int k = 0; k < PBK; ++k) {
      const float4 xv = *(const float4*)(xs + k * XS_STRIDE + trow * 4);
      const float4 wv = *(const float4*)(ws + k * DIM + tcol * 4);
      acc[0][0] += xv.x * wv.x; acc[0][1] += xv.x * wv.y; acc[0][2] += xv.x * wv.z; acc[0][3] += xv.x * wv.w;
      acc[1][0] += xv.y * wv.x; acc[1][1] += xv.y * wv.y; acc[1][2] += xv.y * wv.z; acc[1][3] += xv.y * wv.w;
      acc[2][0] += xv.z * wv.x; acc[2][1] += xv.z * wv.y; acc[2][2] += xv.z * wv.z; acc[2][3] += xv.z * wv.w;
      acc[3][0] += xv.w * wv.x; acc[3][1] += xv.w * wv.y; acc[3][2] += xv.w * wv.z; acc[3][3] += xv.w * wv.w;
    }
  }

  const int colBase = tcol * 4;
  const float4 bv = *(const float4*)(b + colBase);
  #pragma unroll
  for (int i = 0; i < 4; ++i) {
    const int gn = nodeBase + trow * 4 + i;
    if (gn < N_NODES) {
      float4 o;
      o.x = acc[i][0] + bv.x; o.y = acc[i][1] + bv.y;
      o.z = acc[i][2] + bv.z; o.w = acc[i][3] + bv.w;
      *(float4*)(h + (size_t)gn * DIM + colBase) = o;
    }
  }
}

// ---------------------------------------------------------------------------
// xl = h @ wl + bl ; xr = h @ wr + br   (K = 32, cols = 32)
// thread = (node, col); weights in LDS; h row broadcast across 32 lanes.
// ---------------------------------------------------------------------------
__global__ __launch_bounds__(256) void lgemm_kernel(
    const float* __restrict__ h,
    const float* __restrict__ wl, const float* __restrict__ bl,
    const float* __restrict__ wr, const float* __restrict__ br,
    float* __restrict__ xl, float* __restrict__ xr) {
  __shared__ float wls[DIM * DIM];
  __shared__ float wrs[DIM * DIM];
  const int t = threadIdx.x;
  for (int i = t; i < DIM * DIM; i += 256) { wls[i] = wl[i]; wrs[i] = wr[i]; }
  __syncthreads();
  const int node = blockIdx.x * 8 + (t >> 5);
  const int col = t & 31;
  if (node >= N_NODES) return;
  const float* hrow = h + (size_t)node * DIM;
  float al = bl[col], ar = br[col];
  #pragma unroll
  for (int k = 0; k < DIM; ++k) {
    const float hv = hrow[k];
    al += hv * wls[k * DIM + col];
    ar += hv * wrs[k * DIM + col];
  }
  xl[(size_t)node * DIM + col] = al;
  xr[(size_t)node * DIM + col] = ar;
}

// ---------------------------------------------------------------------------
// CSR build: count -> scan -> scatter
// ---------------------------------------------------------------------------
__global__ __launch_bounds__(256) void count_kernel(const int* __restrict__ dst,
                                                    int* __restrict__ cnt) {
  const int i = blockIdx.x * 256 + threadIdx.x;
  if (i < N_EDGES) atomicAdd(&cnt[dst[i]], 1);
}

__global__ __launch_bounds__(1024) void scan_kernel(const int* __restrict__ cnt,
                                                    int* __restrict__ offs) {
  __shared__ int wsum[16];
  __shared__ int srun;
  const int t = threadIdx.x;
  const int lane = t & 63;
  const int wid = t >> 6;
  if (t == 0) srun = 0;
  __syncthreads();
  for (int base = 0; base < N_NODES; base += 1024) {
    const int inb = (base + t < N_NODES);
    const int v = inb ? cnt[base + t] : 0;
    int incl = v;
    #pragma unroll
    for (int off = 1; off < 64; off <<= 1) {
      const int nv = __shfl_up(incl, off, 64);
      if (lane >= off) incl += nv;
    }
    if (lane == 63) wsum[wid] = incl;
    __syncthreads();
    int wpre = 0;
    for (int i = 0; i < wid; ++i) wpre += wsum[i];
    const int run = srun;
    __syncthreads();                       // everyone has read srun & wsum
    if (inb) offs[base + t] = run + wpre + incl - v;   // exclusive prefix
    if (t == 1023) srun = run + wpre + incl;
    __syncthreads();
  }
  if (t == 0) offs[N_NODES] = N_EDGES;
}

__global__ __launch_bounds__(256) void scatter_kernel(
    const int* __restrict__ src, const int* __restrict__ dst,
    const int* __restrict__ offs, int* __restrict__ cursor,
    int* __restrict__ srcs) {
  const int i = blockIdx.x * 256 + threadIdx.x;
  if (i < N_EDGES) {
    const int d = dst[i];
    const int pos = offs[d] + atomicAdd(&cursor[d], 1);
    srcs[pos] = src[i];
  }
}

// ---------------------------------------------------------------------------
// GATv2 edge aggregation, dst-centric. thread = (node, head).
// softmax max-subtraction skipped (logits are O(0.1); shift-invariant).
// hout[n] = hin[n] + conv_bias + (sum_e ex * xl[src]) / max(sum_e ex, 1e-16)
// ---------------------------------------------------------------------------
__global__ __launch_bounds__(256) void gat_edge_kernel(
    const float* __restrict__ hin, const float* __restrict__ xl,
    const float* __restrict__ xr, const float* __restrict__ att,
    const float* __restrict__ cbias, const int* __restrict__ offs,
    const int* __restrict__ srcs, float* __restrict__ hout) {
  const int t = threadIdx.x;
  const int node = blockIdx.x * 32 + (t >> 3);
  const int head = t & 7;
  if (node >= N_NODES) return;
  const float4 a4 = *(const float4*)(att + head * 4);
  const float4 r4 = *(const float4*)(xr + (size_t)node * DIM + head * 4);
  const int beg = offs[node];
  const int end = offs[node + 1];
  float den = 0.f, acc0 = 0.f, acc1 = 0.f, acc2 = 0.f, acc3 = 0.f;
  for (int i = beg; i < end; ++i) {
    const int s = srcs[i];
    const float4 l4 = *(const float4*)(xl + (size_t)s * DIM + head * 4);
    float e0 = l4.x + r4.x; e0 = (e0 > 0.f) ? e0 : 0.2f * e0;
    float e1 = l4.y + r4.y; e1 = (e1 > 0.f) ? e1 : 0.2f * e1;
    float e2 = l4.z + r4.z; e2 = (e2 > 0.f) ? e2 : 0.2f * e2;
    float e3 = l4.w + r4.w; e3 = (e3 > 0.f) ? e3 : 0.2f * e3;
    const float logit = e0 * a4.x + e1 * a4.y + e2 * a4.z + e3 * a4.w;
    const float wgt = __expf(logit);
    den += wgt;
    acc0 += wgt * l4.x; acc1 += wgt * l4.y; acc2 += wgt * l4.z; acc3 += wgt * l4.w;
  }
  const float inv = 1.f / fmaxf(den, 1e-16f);
  const int o = node * DIM + head * 4;
  const float4 hv = *(const float4*)(hin + o);
  const float4 cb = *(const float4*)(cbias + head * 4);
  float4 out;
  out.x = hv.x + cb.x + acc0 * inv;
  out.y = hv.y + cb.y + acc1 * inv;
  out.z = hv.z + cb.z + acc2 * inv;
  out.w = hv.w + cb.w + acc3 * inv;
  *(float4*)(hout + o) = out;
}

// ---------------------------------------------------------------------------
// pred: out[n][j] = sum_k h[n][k] * w[k][j] + b[j], j < 7
// ---------------------------------------------------------------------------
__global__ __launch_bounds__(256) void pred_kernel(
    const float* __restrict__ h, const float* __restrict__ w,
    const float* __restrict__ b, float* __restrict__ out) {
  __shared__ float wsm[DIM * NUM_CLASS];
  __shared__ float bsm[NUM_CLASS];
  const int t = threadIdx.x;
  if (t < DIM * NUM_CLASS) wsm[t] = w[t];
  if (t < NUM_CLASS) bsm[t] = b[t];
  __syncthreads();
  const int n = blockIdx.x * 256 + t;
  if (n >= N_NODES) return;
  float acc[NUM_CLASS];
  #pragma unroll
  for (int j = 0; j < NUM_CLASS; ++j) acc[j] = bsm[j];
  const float* hr = h + (size_t)n * DIM;
  #pragma unroll
  for (int k = 0; k < DIM; k += 4) {
    const float4 hv = *(const float4*)(hr + k);
    #pragma unroll
    for (int j = 0; j < NUM_CLASS; ++j) {
      acc[j] += hv.x * wsm[(k + 0) * NUM_CLASS + j];
      acc[j] += hv.y * wsm[(k + 1) * NUM_CLASS + j];
      acc[j] += hv.z * wsm[(k + 2) * NUM_CLASS + j];
      acc[j] += hv.w * wsm[(k + 3) * NUM_CLASS + j];
    }
  }
  #pragma unroll
  for (int j = 0; j < NUM_CLASS; ++j) out[(size_t)n * NUM_CLASS + j] = acc[j];
}

// ---------------------------------------------------------------------------
extern "C" void kernel_launch(void* const* d_in, const int* in_sizes, int n_in,
                              void* d_out, int out_size, void* d_ws, size_t ws_size,
                              hipStream_t stream) {
  const float* x       = (const float*)d_in[0];
  const int*   ei      = (const int*)d_in[1];
  const float* w_proj  = (const float*)d_in[2];
  const float* b_proj  = (const float*)d_in[3];
  const float* w_l     = (const float*)d_in[4];
  const float* b_l     = (const float*)d_in[5];
  const float* w_r     = (const float*)d_in[6];
  const float* b_r     = (const float*)d_in[7];
  const float* att     = (const float*)d_in[8];
  const float* cbias   = (const float*)d_in[9];
  const float* w_pred  = (const float*)d_in[10];
  const float* b_pred  = (const float*)d_in[11];

  const int* e_src = ei;
  const int* e_dst = ei + N_EDGES;

  char* wsp = (char*)d_ws;
  size_t off = 0;
  auto take = [&](size_t bytes) -> void* {
    void* p = wsp + off;
    off += (bytes + 255) & ~(size_t)255;
    return p;
  };
  float* h0   = (float*)take((size_t)N_NODES * DIM * 4);
  float* h1   = (float*)take((size_t)N_NODES * DIM * 4);
  float* xl   = (float*)take((size_t)N_NODES * DIM * 4);
  float* xr   = (float*)take((size_t)N_NODES * DIM * 4);
  int*   offs = (int*)take((size_t)(N_NODES + 1) * 4);
  int*   cnt  = (int*)take((size_t)N_NODES * 4);
  int*   srcs = (int*)take((size_t)N_EDGES * 4);

  // 1. projection
  proj_kernel<<<(N_NODES + PBM - 1) / PBM, 256, 0, stream>>>(x, w_proj, b_proj, h0);

  // 2. CSR build (dst-sorted edge list), reused by both layers
  hipMemsetAsync(cnt, 0, (size_t)N_NODES * 4, stream);
  count_kernel<<<(N_EDGES + 255) / 256, 256, 0, stream>>>(e_dst, cnt);
  scan_kernel<<<1, 1024, 0, stream>>>(cnt, offs);
  hipMemsetAsync(cnt, 0, (size_t)N_NODES * 4, stream);
  scatter_kernel<<<(N_EDGES + 255) / 256, 256, 0, stream>>>(e_src, e_dst, offs, cnt, srcs);

  // 3. GAT layers
  float* hin = h0;
  float* hout = h1;
  for (int layer = 0; layer < 2; ++layer) {
    lgemm_kernel<<<(N_NODES + 7) / 8, 256, 0, stream>>>(
        hin, w_l + layer * DIM * DIM, b_l + layer * DIM,
        w_r + layer * DIM * DIM, b_r + layer * DIM, xl, xr);
    gat_edge_kernel<<<(N_NODES + 31) / 32, 256, 0, stream>>>(
        hin, xl, xr, att + layer * HEADS * OUT_C, cbias + layer * DIM,
        offs, srcs, hout);
    float* tmp = hin; hin = hout; hout = tmp;
  }

  // 4. prediction head
  pred_kernel<<<(N_NODES + 255) / 256, 256, 0, stream>>>(hin, w_pred, b_pred, (float*)d_out);
}

// Round 2
// 881.777 us; speedup vs baseline: 1.5384x; 1.5384x over previous
//
#include <hip/hip_runtime.h>

#define N_NODES 100000
#define N_EDGES 3200000
#define IN_C 1433
#define DIM 32
#define HEADS 8
#define OUT_C 4
#define NUM_CLASS 7

typedef __bf16 bf16x8 __attribute__((ext_vector_type(8)));
typedef float f32x4 __attribute__((ext_vector_type(4)));

// ---------------------------------------------------------------------------
// proj via bf16 MFMA: h[n][c] = sum_k x[n][k] * w[k][c] + b[c]
// block = 32 nodes, 128 threads (2 waves; wave w owns nodes w*16..w*16+15).
// K-loop: 45 steps of 32 (zero-padded past 1433). x converted fp32->bf16
// in-flight; HBM-bound on the single read of x (573 MB).
// ---------------------------------------------------------------------------
#define BSTRIDE 40   // b_lds row stride in bf16: 16B-aligned (80B), low conflicts

__global__ __launch_bounds__(128) void proj_mfma_kernel(
    const float* __restrict__ x, const float* __restrict__ w,
    const float* __restrict__ b, float* __restrict__ h) {
  __shared__ __bf16 a_lds[32 * 32];        // [row][k], row stride 32 (64 B)
  __shared__ __bf16 b_lds[32 * BSTRIDE];   // [col][k], stride 40 (80 B)
  const int t = threadIdx.x;
  const int wid = t >> 6;
  const int lane = t & 63;
  const int nodeBase = blockIdx.x * 32;    // 3125 * 32 = 100000 exactly

  f32x4 acc0 = {0.f, 0.f, 0.f, 0.f};
  f32x4 acc1 = {0.f, 0.f, 0.f, 0.f};

  // fragment read pointers (loop-invariant)
  const int l15 = lane & 15;
  const int kg = lane >> 4;                // k-group 0..3, 8 bf16 each
  const __bf16* aptr  = &a_lds[(wid * 16 + l15) * 32 + kg * 8];
  const __bf16* bptr0 = &b_lds[l15 * BSTRIDE + kg * 8];
  const __bf16* bptr1 = &b_lds[(16 + l15) * BSTRIDE + kg * 8];

  // staging maps
  const int s_r = t >> 5;                  // 0..3 (A: row group)
  const int s_k = t & 31;                  // A: k within tile
  const int b_c = t & 31;                  // B: col
  const int b_k = t >> 5;                  // 0..3 (B: k group)

  for (int k0 = 0; k0 < 1440; k0 += 32) {
    __syncthreads();
    // stage A: 32 rows x 32 k fp32 -> bf16. wave reads 2 rows x 32 consecutive
    // floats per pass (coalesced 128-B segments).
    #pragma unroll
    for (int i = 0; i < 8; ++i) {
      const int r = s_r + 4 * i;
      const int gk = k0 + s_k;
      float v = 0.f;
      if (gk < IN_C) v = x[(size_t)(nodeBase + r) * IN_C + gk];
      a_lds[r * 32 + s_k] = (__bf16)v;
    }
    // stage B: w[k][c] -> b_lds[c][k]
    #pragma unroll
    for (int i = 0; i < 8; ++i) {
      const int kk = b_k + 4 * i;
      const int gk = k0 + kk;
      float v = 0.f;
      if (gk < IN_C) v = w[(size_t)gk * DIM + b_c];
      b_lds[b_c * BSTRIDE + kk] = (__bf16)v;
    }
    __syncthreads();

    const bf16x8 af  = *(const bf16x8*)aptr;
    const bf16x8 bf0 = *(const bf16x8*)bptr0;
    const bf16x8 bf1 = *(const bf16x8*)bptr1;
    acc0 = __builtin_amdgcn_mfma_f32_16x16x32_bf16(af, bf0, acc0, 0, 0, 0);
    acc1 = __builtin_amdgcn_mfma_f32_16x16x32_bf16(af, bf1, acc1, 0, 0, 0);
  }

  // C/D layout: col = lane&15, row = (lane>>4)*4 + reg
  const int col = l15;
  const int rbase = nodeBase + wid * 16 + kg * 4;
  const float bc0 = b[col];
  const float bc1 = b[col + 16];
  #pragma unroll
  for (int rg = 0; rg < 4; ++rg) {
    h[(size_t)(rbase + rg) * DIM + col]      = acc0[rg] + bc0;
    h[(size_t)(rbase + rg) * DIM + col + 16] = acc1[rg] + bc1;
  }
}

// ---------------------------------------------------------------------------
// xl = h @ wl + bl ; xr = h @ wr + br   (K = 32, cols = 32)
// ---------------------------------------------------------------------------
__global__ __launch_bounds__(256) void lgemm_kernel(
    const float* __restrict__ h,
    const float* __restrict__ wl, const float* __restrict__ bl,
    const float* __restrict__ wr, const float* __restrict__ br,
    float* __restrict__ xl, float* __restrict__ xr) {
  __shared__ float wls[DIM * DIM];
  __shared__ float wrs[DIM * DIM];
  const int t = threadIdx.x;
  for (int i = t; i < DIM * DIM; i += 256) { wls[i] = wl[i]; wrs[i] = wr[i]; }
  __syncthreads();
  const int node = blockIdx.x * 8 + (t >> 5);
  const int col = t & 31;
  if (node >= N_NODES) return;
  const float* hrow = h + (size_t)node * DIM;
  float al = bl[col], ar = br[col];
  #pragma unroll
  for (int k = 0; k < DIM; ++k) {
    const float hv = hrow[k];
    al += hv * wls[k * DIM + col];
    ar += hv * wrs[k * DIM + col];
  }
  xl[(size_t)node * DIM + col] = al;
  xr[(size_t)node * DIM + col] = ar;
}

// ---------------------------------------------------------------------------
// CSR build: count -> scan -> scatter
// ---------------------------------------------------------------------------
__global__ __launch_bounds__(256) void count_kernel(const int* __restrict__ dst,
                                                    int* __restrict__ cnt) {
  const int i = blockIdx.x * 256 + threadIdx.x;
  if (i < N_EDGES) atomicAdd(&cnt[dst[i]], 1);
}

__global__ __launch_bounds__(1024) void scan_kernel(const int* __restrict__ cnt,
                                                    int* __restrict__ offs) {
  __shared__ int wsum[16];
  __shared__ int srun;
  const int t = threadIdx.x;
  const int lane = t & 63;
  const int wid = t >> 6;
  if (t == 0) srun = 0;
  __syncthreads();
  for (int base = 0; base < N_NODES; base += 1024) {
    const int inb = (base + t < N_NODES);
    const int v = inb ? cnt[base + t] : 0;
    int incl = v;
    #pragma unroll
    for (int off = 1; off < 64; off <<= 1) {
      const int nv = __shfl_up(incl, off, 64);
      if (lane >= off) incl += nv;
    }
    if (lane == 63) wsum[wid] = incl;
    __syncthreads();
    int wpre = 0;
    for (int i = 0; i < wid; ++i) wpre += wsum[i];
    const int run = srun;
    __syncthreads();
    if (inb) offs[base + t] = run + wpre + incl - v;
    if (t == 1023) srun = run + wpre + incl;
    __syncthreads();
  }
  if (t == 0) offs[N_NODES] = N_EDGES;
}

__global__ __launch_bounds__(256) void scatter_kernel(
    const int* __restrict__ src, const int* __restrict__ dst,
    const int* __restrict__ offs, int* __restrict__ cursor,
    int* __restrict__ srcs) {
  const int i = blockIdx.x * 256 + threadIdx.x;
  if (i < N_EDGES) {
    const int d = dst[i];
    const int pos = offs[d] + atomicAdd(&cursor[d], 1);
    srcs[pos] = src[i];
  }
}

// ---------------------------------------------------------------------------
// GATv2 edge aggregation, dst-centric. thread = (node, head).
// ---------------------------------------------------------------------------
__global__ __launch_bounds__(256) void gat_edge_kernel(
    const float* __restrict__ hin, const float* __restrict__ xl,
    const float* __restrict__ xr, const float* __restrict__ att,
    const float* __restrict__ cbias, const int* __restrict__ offs,
    const int* __restrict__ srcs, float* __restrict__ hout) {
  const int t = threadIdx.x;
  const int node = blockIdx.x * 32 + (t >> 3);
  const int head = t & 7;
  if (node >= N_NODES) return;
  const float4 a4 = *(const float4*)(att + head * 4);
  const float4 r4 = *(const float4*)(xr + (size_t)node * DIM + head * 4);
  const int beg = offs[node];
  const int end = offs[node + 1];
  float den = 0.f, acc0 = 0.f, acc1 = 0.f, acc2 = 0.f, acc3 = 0.f;
  for (int i = beg; i < end; ++i) {
    const int s = srcs[i];
    const float4 l4 = *(const float4*)(xl + (size_t)s * DIM + head * 4);
    float e0 = l4.x + r4.x; e0 = (e0 > 0.f) ? e0 : 0.2f * e0;
    float e1 = l4.y + r4.y; e1 = (e1 > 0.f) ? e1 : 0.2f * e1;
    float e2 = l4.z + r4.z; e2 = (e2 > 0.f) ? e2 : 0.2f * e2;
    float e3 = l4.w + r4.w; e3 = (e3 > 0.f) ? e3 : 0.2f * e3;
    const float logit = e0 * a4.x + e1 * a4.y + e2 * a4.z + e3 * a4.w;
    const float wgt = __expf(logit);
    den += wgt;
    acc0 += wgt * l4.x; acc1 += wgt * l4.y; acc2 += wgt * l4.z; acc3 += wgt * l4.w;
  }
  const float inv = 1.f / fmaxf(den, 1e-16f);
  const int o = node * DIM + head * 4;
  const float4 hv = *(const float4*)(hin + o);
  const float4 cb = *(const float4*)(cbias + head * 4);
  float4 out;
  out.x = hv.x + cb.x + acc0 * inv;
  out.y = hv.y + cb.y + acc1 * inv;
  out.z = hv.z + cb.z + acc2 * inv;
  out.w = hv.w + cb.w + acc3 * inv;
  *(float4*)(hout + o) = out;
}

// ---------------------------------------------------------------------------
// pred: out[n][j] = sum_k h[n][k] * w[k][j] + b[j], j < 7
// ---------------------------------------------------------------------------
__global__ __launch_bounds__(256) void pred_kernel(
    const float* __restrict__ h, const float* __restrict__ w,
    const float* __restrict__ b, float* __restrict__ out) {
  __shared__ float wsm[DIM * NUM_CLASS];
  __shared__ float bsm[NUM_CLASS];
  const int t = threadIdx.x;
  if (t < DIM * NUM_CLASS) wsm[t] = w[t];
  if (t < NUM_CLASS) bsm[t] = b[t];
  __syncthreads();
  const int n = blockIdx.x * 256 + t;
  if (n >= N_NODES) return;
  float acc[NUM_CLASS];
  #pragma unroll
  for (int j = 0; j < NUM_CLASS; ++j) acc[j] = bsm[j];
  const float* hr = h + (size_t)n * DIM;
  #pragma unroll
  for (int k = 0; k < DIM; k += 4) {
    const float4 hv = *(const float4*)(hr + k);
    #pragma unroll
    for (int j = 0; j < NUM_CLASS; ++j) {
      acc[j] += hv.x * wsm[(k + 0) * NUM_CLASS + j];
      acc[j] += hv.y * wsm[(k + 1) * NUM_CLASS + j];
      acc[j] += hv.z * wsm[(k + 2) * NUM_CLASS + j];
      acc[j] += hv.w * wsm[(k + 3) * NUM_CLASS + j];
    }
  }
  #pragma unroll
  for (int j = 0; j < NUM_CLASS; ++j) out[(size_t)n * NUM_CLASS + j] = acc[j];
}

// ---------------------------------------------------------------------------
extern "C" void kernel_launch(void* const* d_in, const int* in_sizes, int n_in,
                              void* d_out, int out_size, void* d_ws, size_t ws_size,
                              hipStream_t stream) {
  const float* x       = (const float*)d_in[0];
  const int*   ei      = (const int*)d_in[1];
  const float* w_proj  = (const float*)d_in[2];
  const float* b_proj  = (const float*)d_in[3];
  const float* w_l     = (const float*)d_in[4];
  const float* b_l     = (const float*)d_in[5];
  const float* w_r     = (const float*)d_in[6];
  const float* b_r     = (const float*)d_in[7];
  const float* att     = (const float*)d_in[8];
  const float* cbias   = (const float*)d_in[9];
  const float* w_pred  = (const float*)d_in[10];
  const float* b_pred  = (const float*)d_in[11];

  const int* e_src = ei;
  const int* e_dst = ei + N_EDGES;

  char* wsp = (char*)d_ws;
  size_t off = 0;
  auto take = [&](size_t bytes) -> void* {
    void* p = wsp + off;
    off += (bytes + 255) & ~(size_t)255;
    return p;
  };
  float* h0   = (float*)take((size_t)N_NODES * DIM * 4);
  float* h1   = (float*)take((size_t)N_NODES * DIM * 4);
  float* xl   = (float*)take((size_t)N_NODES * DIM * 4);
  float* xr   = (float*)take((size_t)N_NODES * DIM * 4);
  int*   offs = (int*)take((size_t)(N_NODES + 1) * 4);
  int*   cnt  = (int*)take((size_t)N_NODES * 4);
  int*   srcs = (int*)take((size_t)N_EDGES * 4);

  // 1. projection (bf16 MFMA, HBM-bound on x)
  proj_mfma_kernel<<<N_NODES / 32, 128, 0, stream>>>(x, w_proj, b_proj, h0);

  // 2. CSR build (dst-sorted edge list), reused by both layers
  hipMemsetAsync(cnt, 0, (size_t)N_NODES * 4, stream);
  count_kernel<<<(N_EDGES + 255) / 256, 256, 0, stream>>>(e_dst, cnt);
  scan_kernel<<<1, 1024, 0, stream>>>(cnt, offs);
  hipMemsetAsync(cnt, 0, (size_t)N_NODES * 4, stream);
  scatter_kernel<<<(N_EDGES + 255) / 256, 256, 0, stream>>>(e_src, e_dst, offs, cnt, srcs);

  // 3. GAT layers
  float* hin = h0;
  float* hout = h1;
  for (int layer = 0; layer < 2; ++layer) {
    lgemm_kernel<<<(N_NODES + 7) / 8, 256, 0, stream>>>(
        hin, w_l + layer * DIM * DIM, b_l + layer * DIM,
        w_r + layer * DIM * DIM, b_r + layer * DIM, xl, xr);
    gat_edge_kernel<<<(N_NODES + 31) / 32, 256, 0, stream>>>(
        hin, xl, xr, att + layer * HEADS * OUT_C, cbias + layer * DIM,
        offs, srcs, hout);
    float* tmp = hin; hin = hout; hout = tmp;
  }

  // 4. prediction head
  pred_kernel<<<(N_NODES + 255) / 256, 256, 0, stream>>>(hin, w_pred, b_pred, (float*)d_out);
}

// Round 3
// 756.029 us; speedup vs baseline: 1.7943x; 1.1663x over previous
//
#include <hip/hip_runtime.h>

#define N_NODES 100000
#define N_EDGES 3200000
#define IN_C 1433
#define DIM 32
#define HEADS 8
#define OUT_C 4
#define NUM_CLASS 7

#define KTILES 45           // ceil(1433/32); tile 44 is the masked tail
#define N_WAVES 6250        // 100000 / 16 nodes per wave

typedef __bf16 bf16x8 __attribute__((ext_vector_type(8)));
typedef float f32x4 __attribute__((ext_vector_type(4)));

// ---------------------------------------------------------------------------
// prep_w: pack w[k][c] (fp32) into per-lane MFMA B-fragments (bf16), zero-
// padded past k=1433. Layout: wfrag[(kt*2 + colhalf)*64 + lane] = bf16x8 with
// element e = w[kt*32 + (lane>>4)*8 + e][colhalf*16 + (lane&15)].
// 90 KB total; L2-resident during proj.
// ---------------------------------------------------------------------------
__global__ __launch_bounds__(64) void prep_w_kernel(
    const float* __restrict__ w, bf16x8* __restrict__ wfrag) {
  const int kt = blockIdx.x >> 1;
  const int ch = blockIdx.x & 1;
  const int l = threadIdx.x;
  const int col = ch * 16 + (l & 15);
  const int kbase = kt * 32 + (l >> 4) * 8;
  bf16x8 v;
  #pragma unroll
  for (int e = 0; e < 8; ++e) {
    const int k = kbase + e;
    v[e] = (__bf16)((k < IN_C) ? w[(size_t)k * DIM + col] : 0.f);
  }
  wfrag[(size_t)blockIdx.x * 64 + l] = v;
}

// ---------------------------------------------------------------------------
// proj: h = x @ w + b via bf16 MFMA, LDS-free.
// wave = 16 nodes x 32 cols. A loaded global->reg (8 consecutive floats per
// lane per tile), B from pre-packed wfrag. HBM-bound on the 573 MB x read.
// ---------------------------------------------------------------------------
__global__ __launch_bounds__(256) void proj_mfma_kernel(
    const float* __restrict__ x, const bf16x8* __restrict__ wfrag,
    const float* __restrict__ b, float* __restrict__ h) {
  const int t = threadIdx.x;
  const int lane = t & 63;
  const int widx = blockIdx.x * 4 + (t >> 6);
  if (widx >= N_WAVES) return;
  const int nodeBase = widx * 16;
  const int row = lane & 15;
  const int kg = lane >> 4;

  const float* xp = x + (size_t)(nodeBase + row) * IN_C + kg * 8;
  const bf16x8* wp = wfrag + lane;

  f32x4 acc0 = {0.f, 0.f, 0.f, 0.f};
  f32x4 acc1 = {0.f, 0.f, 0.f, 0.f};

  #pragma unroll 4
  for (int kt = 0; kt < KTILES - 1; ++kt) {
    bf16x8 af;
    #pragma unroll
    for (int e = 0; e < 8; ++e) af[e] = (__bf16)xp[e];
    const bf16x8 b0 = wp[(kt * 2 + 0) * 64];
    const bf16x8 b1 = wp[(kt * 2 + 1) * 64];
    acc0 = __builtin_amdgcn_mfma_f32_16x16x32_bf16(af, b0, acc0, 0, 0, 0);
    acc1 = __builtin_amdgcn_mfma_f32_16x16x32_bf16(af, b1, acc1, 0, 0, 0);
    xp += 32;
  }
  {  // tail tile kt = 44: k = 1408 + kg*8 + e valid iff kg*8+e < 25
    bf16x8 af;
    #pragma unroll
    for (int e = 0; e < 8; ++e)
      af[e] = (__bf16)((kg * 8 + e < IN_C - 1408) ? xp[e] : 0.f);
    const bf16x8 b0 = wp[((KTILES - 1) * 2 + 0) * 64];
    const bf16x8 b1 = wp[((KTILES - 1) * 2 + 1) * 64];
    acc0 = __builtin_amdgcn_mfma_f32_16x16x32_bf16(af, b0, acc0, 0, 0, 0);
    acc1 = __builtin_amdgcn_mfma_f32_16x16x32_bf16(af, b1, acc1, 0, 0, 0);
  }

  // C/D: col = lane&15, out-row = kg*4 + reg
  const float bc0 = b[row];        // row == lane&15 doubles as output col
  const float bc1 = b[row + 16];
  #pragma unroll
  for (int rg = 0; rg < 4; ++rg) {
    const size_t o = (size_t)(nodeBase + kg * 4 + rg) * DIM + row;
    h[o] = acc0[rg] + bc0;
    h[o + 16] = acc1[rg] + bc1;
  }
}

// ---------------------------------------------------------------------------
// xl = h @ wl + bl ; xr = h @ wr + br   (K = 32, cols = 32)
// ---------------------------------------------------------------------------
__global__ __launch_bounds__(256) void lgemm_kernel(
    const float* __restrict__ h,
    const float* __restrict__ wl, const float* __restrict__ bl,
    const float* __restrict__ wr, const float* __restrict__ br,
    float* __restrict__ xl, float* __restrict__ xr) {
  __shared__ float wls[DIM * DIM];
  __shared__ float wrs[DIM * DIM];
  const int t = threadIdx.x;
  for (int i = t; i < DIM * DIM; i += 256) { wls[i] = wl[i]; wrs[i] = wr[i]; }
  __syncthreads();
  const int node = blockIdx.x * 8 + (t >> 5);
  const int col = t & 31;
  if (node >= N_NODES) return;
  const float* hrow = h + (size_t)node * DIM;
  float al = bl[col], ar = br[col];
  #pragma unroll
  for (int k = 0; k < DIM; ++k) {
    const float hv = hrow[k];
    al += hv * wls[k * DIM + col];
    ar += hv * wrs[k * DIM + col];
  }
  xl[(size_t)node * DIM + col] = al;
  xr[(size_t)node * DIM + col] = ar;
}

// ---------------------------------------------------------------------------
// CSR build: count -> scan -> scatter
// ---------------------------------------------------------------------------
__global__ __launch_bounds__(256) void count_kernel(const int* __restrict__ dst,
                                                    int* __restrict__ cnt) {
  const int i = blockIdx.x * 256 + threadIdx.x;
  if (i < N_EDGES) atomicAdd(&cnt[dst[i]], 1);
}

__global__ __launch_bounds__(1024) void scan_kernel(const int* __restrict__ cnt,
                                                    int* __restrict__ offs) {
  __shared__ int wsum[16];
  __shared__ int srun;
  const int t = threadIdx.x;
  const int lane = t & 63;
  const int wid = t >> 6;
  if (t == 0) srun = 0;
  __syncthreads();
  for (int base = 0; base < N_NODES; base += 1024) {
    const int inb = (base + t < N_NODES);
    const int v = inb ? cnt[base + t] : 0;
    int incl = v;
    #pragma unroll
    for (int off = 1; off < 64; off <<= 1) {
      const int nv = __shfl_up(incl, off, 64);
      if (lane >= off) incl += nv;
    }
    if (lane == 63) wsum[wid] = incl;
    __syncthreads();
    int wpre = 0;
    for (int i = 0; i < wid; ++i) wpre += wsum[i];
    const int run = srun;
    __syncthreads();
    if (inb) offs[base + t] = run + wpre + incl - v;
    if (t == 1023) srun = run + wpre + incl;
    __syncthreads();
  }
  if (t == 0) offs[N_NODES] = N_EDGES;
}

__global__ __launch_bounds__(256) void scatter_kernel(
    const int* __restrict__ src, const int* __restrict__ dst,
    const int* __restrict__ offs, int* __restrict__ cursor,
    int* __restrict__ srcs) {
  const int i = blockIdx.x * 256 + threadIdx.x;
  if (i < N_EDGES) {
    const int d = dst[i];
    const int pos = offs[d] + atomicAdd(&cursor[d], 1);
    srcs[pos] = src[i];
  }
}

// ---------------------------------------------------------------------------
// GATv2 edge aggregation, dst-centric. thread = (node, head).
// ---------------------------------------------------------------------------
__global__ __launch_bounds__(256) void gat_edge_kernel(
    const float* __restrict__ hin, const float* __restrict__ xl,
    const float* __restrict__ xr, const float* __restrict__ att,
    const float* __restrict__ cbias, const int* __restrict__ offs,
    const int* __restrict__ srcs, float* __restrict__ hout) {
  const int t = threadIdx.x;
  const int node = blockIdx.x * 32 + (t >> 3);
  const int head = t & 7;
  if (node >= N_NODES) return;
  const float4 a4 = *(const float4*)(att + head * 4);
  const float4 r4 = *(const float4*)(xr + (size_t)node * DIM + head * 4);
  const int beg = offs[node];
  const int end = offs[node + 1];
  float den = 0.f, acc0 = 0.f, acc1 = 0.f, acc2 = 0.f, acc3 = 0.f;
  for (int i = beg; i < end; ++i) {
    const int s = srcs[i];
    const float4 l4 = *(const float4*)(xl + (size_t)s * DIM + head * 4);
    float e0 = l4.x + r4.x; e0 = (e0 > 0.f) ? e0 : 0.2f * e0;
    float e1 = l4.y + r4.y; e1 = (e1 > 0.f) ? e1 : 0.2f * e1;
    float e2 = l4.z + r4.z; e2 = (e2 > 0.f) ? e2 : 0.2f * e2;
    float e3 = l4.w + r4.w; e3 = (e3 > 0.f) ? e3 : 0.2f * e3;
    const float logit = e0 * a4.x + e1 * a4.y + e2 * a4.z + e3 * a4.w;
    const float wgt = __expf(logit);
    den += wgt;
    acc0 += wgt * l4.x; acc1 += wgt * l4.y; acc2 += wgt * l4.z; acc3 += wgt * l4.w;
  }
  const float inv = 1.f / fmaxf(den, 1e-16f);
  const int o = node * DIM + head * 4;
  const float4 hv = *(const float4*)(hin + o);
  const float4 cb = *(const float4*)(cbias + head * 4);
  float4 out;
  out.x = hv.x + cb.x + acc0 * inv;
  out.y = hv.y + cb.y + acc1 * inv;
  out.z = hv.z + cb.z + acc2 * inv;
  out.w = hv.w + cb.w + acc3 * inv;
  *(float4*)(hout + o) = out;
}

// ---------------------------------------------------------------------------
// pred: out[n][j] = sum_k h[n][k] * w[k][j] + b[j], j < 7
// ---------------------------------------------------------------------------
__global__ __launch_bounds__(256) void pred_kernel(
    const float* __restrict__ h, const float* __restrict__ w,
    const float* __restrict__ b, float* __restrict__ out) {
  __shared__ float wsm[DIM * NUM_CLASS];
  __shared__ float bsm[NUM_CLASS];
  const int t = threadIdx.x;
  if (t < DIM * NUM_CLASS) wsm[t] = w[t];
  if (t < NUM_CLASS) bsm[t] = b[t];
  __syncthreads();
  const int n = blockIdx.x * 256 + t;
  if (n >= N_NODES) return;
  float acc[NUM_CLASS];
  #pragma unroll
  for (int j = 0; j < NUM_CLASS; ++j) acc[j] = bsm[j];
  const float* hr = h + (size_t)n * DIM;
  #pragma unroll
  for (int k = 0; k < DIM; k += 4) {
    const float4 hv = *(const float4*)(hr + k);
    #pragma unroll
    for (int j = 0; j < NUM_CLASS; ++j) {
      acc[j] += hv.x * wsm[(k + 0) * NUM_CLASS + j];
      acc[j] += hv.y * wsm[(k + 1) * NUM_CLASS + j];
      acc[j] += hv.z * wsm[(k + 2) * NUM_CLASS + j];
      acc[j] += hv.w * wsm[(k + 3) * NUM_CLASS + j];
    }
  }
  #pragma unroll
  for (int j = 0; j < NUM_CLASS; ++j) out[(size_t)n * NUM_CLASS + j] = acc[j];
}

// ---------------------------------------------------------------------------
extern "C" void kernel_launch(void* const* d_in, const int* in_sizes, int n_in,
                              void* d_out, int out_size, void* d_ws, size_t ws_size,
                              hipStream_t stream) {
  const float* x       = (const float*)d_in[0];
  const int*   ei      = (const int*)d_in[1];
  const float* w_proj  = (const float*)d_in[2];
  const float* b_proj  = (const float*)d_in[3];
  const float* w_l     = (const float*)d_in[4];
  const float* b_l     = (const float*)d_in[5];
  const float* w_r     = (const float*)d_in[6];
  const float* b_r     = (const float*)d_in[7];
  const float* att     = (const float*)d_in[8];
  const float* cbias   = (const float*)d_in[9];
  const float* w_pred  = (const float*)d_in[10];
  const float* b_pred  = (const float*)d_in[11];

  const int* e_src = ei;
  const int* e_dst = ei + N_EDGES;

  char* wsp = (char*)d_ws;
  size_t off = 0;
  auto take = [&](size_t bytes) -> void* {
    void* p = wsp + off;
    off += (bytes + 255) & ~(size_t)255;
    return p;
  };
  float*  h0    = (float*)take((size_t)N_NODES * DIM * 4);
  float*  h1    = (float*)take((size_t)N_NODES * DIM * 4);
  float*  xl    = (float*)take((size_t)N_NODES * DIM * 4);
  float*  xr    = (float*)take((size_t)N_NODES * DIM * 4);
  int*    offs  = (int*)take((size_t)(N_NODES + 1) * 4);
  int*    cnt   = (int*)take((size_t)N_NODES * 4);
  int*    srcs  = (int*)take((size_t)N_EDGES * 4);
  bf16x8* wfrag = (bf16x8*)take((size_t)KTILES * 2 * 64 * 16);

  // 1. projection (LDS-free bf16 MFMA, HBM-bound on x)
  prep_w_kernel<<<KTILES * 2, 64, 0, stream>>>(w_proj, wfrag);
  proj_mfma_kernel<<<(N_WAVES + 3) / 4, 256, 0, stream>>>(x, wfrag, b_proj, h0);

  // 2. CSR build (dst-sorted edge list), reused by both layers
  hipMemsetAsync(cnt, 0, (size_t)N_NODES * 4, stream);
  count_kernel<<<(N_EDGES + 255) / 256, 256, 0, stream>>>(e_dst, cnt);
  scan_kernel<<<1, 1024, 0, stream>>>(cnt, offs);
  hipMemsetAsync(cnt, 0, (size_t)N_NODES * 4, stream);
  scatter_kernel<<<(N_EDGES + 255) / 256, 256, 0, stream>>>(e_src, e_dst, offs, cnt, srcs);

  // 3. GAT layers
  float* hin = h0;
  float* hout = h1;
  for (int layer = 0; layer < 2; ++layer) {
    lgemm_kernel<<<(N_NODES + 7) / 8, 256, 0, stream>>>(
        hin, w_l + layer * DIM * DIM, b_l + layer * DIM,
        w_r + layer * DIM * DIM, b_r + layer * DIM, xl, xr);
    gat_edge_kernel<<<(N_NODES + 31) / 32, 256, 0, stream>>>(
        hin, xl, xr, att + layer * HEADS * OUT_C, cbias + layer * DIM,
        offs, srcs, hout);
    float* tmp = hin; hin = hout; hout = tmp;
  }

  // 4. prediction head
  pred_kernel<<<(N_NODES + 255) / 256, 256, 0, stream>>>(hin, w_pred, b_pred, (float*)d_out);
}

// Round 4
// 642.091 us; speedup vs baseline: 2.1127x; 1.1774x over previous
//
#include <hip/hip_runtime.h>

#define N_NODES 100000
#define N_EDGES 3200000
#define IN_C 1433
#define DIM 32
#define HEADS 8
#define OUT_C 4
#define NUM_CLASS 7

#define KTILES 45           // ceil(1433/32); tile 44 is the masked tail
#define N_WAVES 6250        // 100000 / 16 nodes per wave
#define NB_SCAN 98          // ceil(100000/1024)

typedef __bf16 bf16x8 __attribute__((ext_vector_type(8)));
typedef float f32x4 __attribute__((ext_vector_type(4)));

// ---------------------------------------------------------------------------
// prep_w: pack w[k][c] (fp32) into per-lane MFMA B-fragments (bf16), zero-
// padded past k=1433. wfrag[(kt*2 + colhalf)*64 + lane] = bf16x8, element
// e = w[kt*32 + (lane>>4)*8 + e][colhalf*16 + (lane&15)]. 90 KB, L2-resident.
// ---------------------------------------------------------------------------
__global__ __launch_bounds__(64) void prep_w_kernel(
    const float* __restrict__ w, bf16x8* __restrict__ wfrag) {
  const int kt = blockIdx.x >> 1;
  const int ch = blockIdx.x & 1;
  const int l = threadIdx.x;
  const int col = ch * 16 + (l & 15);
  const int kbase = kt * 32 + (l >> 4) * 8;
  bf16x8 v;
  #pragma unroll
  for (int e = 0; e < 8; ++e) {
    const int k = kbase + e;
    v[e] = (__bf16)((k < IN_C) ? w[(size_t)k * DIM + col] : 0.f);
  }
  wfrag[(size_t)blockIdx.x * 64 + l] = v;
}

// ---------------------------------------------------------------------------
// proj: h = x @ w + b via bf16 MFMA. Wave = 16 nodes x 32 cols; each wave
// stages its own 16x32 fp32 tile in a PRIVATE 2KB LDS slab (no barriers).
// Staging loads: 8 coalesced dwords/lane (2 rows x 128B per instruction).
// LDS swizzle: 16B granule p = g ^ (row&7) -> conflict-free writes, ~2-way
// (free) ds_read_b128 fragment reads. HBM-bound on the 573 MB x read.
// ---------------------------------------------------------------------------
__global__ __launch_bounds__(256) void proj_mfma_kernel(
    const float* __restrict__ x, const bf16x8* __restrict__ wfrag,
    const float* __restrict__ b, float* __restrict__ h) {
  __shared__ float stage[4][16 * 32];
  const int t = threadIdx.x;
  const int lane = t & 63;
  const int wid = t >> 6;
  const int widx = blockIdx.x * 4 + wid;
  if (widx >= N_WAVES) return;
  const int nodeBase = widx * 16;
  float* slab = stage[wid];

  // staging map: instruction i covers rows 2i,2i+1; lane -> (srow, col)
  const int srow = lane >> 5;          // 0..1
  const int scol = lane & 31;
  const float* xbase = x + (size_t)(nodeBase + srow) * IN_C + scol;

  // fragment map
  const int frow = lane & 15;
  const int kg = lane >> 4;            // 0..3
  const int sw = frow & 7;
  // read addrs (dword offsets within slab)
  const int rd0 = frow * 32 + (((2 * kg) ^ sw) << 2);
  const int rd1 = frow * 32 + (((2 * kg + 1) ^ sw) << 2);
  const bf16x8* wp = wfrag + lane;

  f32x4 acc0 = {0.f, 0.f, 0.f, 0.f};
  f32x4 acc1 = {0.f, 0.f, 0.f, 0.f};

  float cur[8];
  // prologue: load tile 0
  #pragma unroll
  for (int i = 0; i < 8; ++i) cur[i] = xbase[(size_t)(2 * i) * IN_C];

  for (int kt = 0; kt < KTILES; ++kt) {
    // stage cur -> LDS (swizzled)
    #pragma unroll
    for (int i = 0; i < 8; ++i) {
      const int row = 2 * i + srow;
      const int p = (scol >> 2) ^ (row & 7);
      slab[row * 32 + (p << 2) + (scol & 3)] = cur[i];
    }
    // issue next tile's global loads (overlap with MFMA below)
    if (kt + 1 < KTILES) {
      const int gk = (kt + 1) * 32 + scol;
      const float* xp = xbase + (size_t)(kt + 1) * 32;
      const bool ok = gk < IN_C;
      #pragma unroll
      for (int i = 0; i < 8; ++i)
        cur[i] = ok ? xp[(size_t)(2 * i) * IN_C] : 0.f;
    }
    // fragment read + cvt + MFMA
    const f32x4 lo = *(const f32x4*)(slab + rd0);
    const f32x4 hi = *(const f32x4*)(slab + rd1);
    bf16x8 af;
    af[0] = (__bf16)lo[0]; af[1] = (__bf16)lo[1];
    af[2] = (__bf16)lo[2]; af[3] = (__bf16)lo[3];
    af[4] = (__bf16)hi[0]; af[5] = (__bf16)hi[1];
    af[6] = (__bf16)hi[2]; af[7] = (__bf16)hi[3];
    const bf16x8 b0 = wp[(kt * 2 + 0) * 64];
    const bf16x8 b1 = wp[(kt * 2 + 1) * 64];
    acc0 = __builtin_amdgcn_mfma_f32_16x16x32_bf16(af, b0, acc0, 0, 0, 0);
    acc1 = __builtin_amdgcn_mfma_f32_16x16x32_bf16(af, b1, acc1, 0, 0, 0);
  }

  // C/D: col = lane&15, out-row = kg*4 + reg
  const float bc0 = b[frow];
  const float bc1 = b[frow + 16];
  #pragma unroll
  for (int rg = 0; rg < 4; ++rg) {
    const size_t o = (size_t)(nodeBase + kg * 4 + rg) * DIM + frow;
    h[o] = acc0[rg] + bc0;
    h[o + 16] = acc1[rg] + bc1;
  }
}

// ---------------------------------------------------------------------------
// xl = h @ wl + bl ; xr = h @ wr + br   (K = 32, cols = 32)
// ---------------------------------------------------------------------------
__global__ __launch_bounds__(256) void lgemm_kernel(
    const float* __restrict__ h,
    const float* __restrict__ wl, const float* __restrict__ bl,
    const float* __restrict__ wr, const float* __restrict__ br,
    float* __restrict__ xl, float* __restrict__ xr) {
  __shared__ float wls[DIM * DIM];
  __shared__ float wrs[DIM * DIM];
  const int t = threadIdx.x;
  for (int i = t; i < DIM * DIM; i += 256) { wls[i] = wl[i]; wrs[i] = wr[i]; }
  __syncthreads();
  const int node = blockIdx.x * 8 + (t >> 5);
  const int col = t & 31;
  if (node >= N_NODES) return;
  const float* hrow = h + (size_t)node * DIM;
  float al = bl[col], ar = br[col];
  #pragma unroll
  for (int k = 0; k < DIM; ++k) {
    const float hv = hrow[k];
    al += hv * wls[k * DIM + col];
    ar += hv * wrs[k * DIM + col];
  }
  xl[(size_t)node * DIM + col] = al;
  xr[(size_t)node * DIM + col] = ar;
}

// ---------------------------------------------------------------------------
// CSR build: count -> hierarchical scan (3 kernels) -> scatter
// ---------------------------------------------------------------------------
__global__ __launch_bounds__(256) void count_kernel(const int* __restrict__ dst,
                                                    int* __restrict__ cnt) {
  const int i = blockIdx.x * 256 + threadIdx.x;
  if (i < N_EDGES) atomicAdd(&cnt[dst[i]], 1);
}

// block-local exclusive scan of 1024 elements; writes partial to offs, block
// total to bsum.
__global__ __launch_bounds__(1024) void scan_local_kernel(
    const int* __restrict__ cnt, int* __restrict__ offs, int* __restrict__ bsum) {
  __shared__ int wsum[16];
  const int t = threadIdx.x;
  const int lane = t & 63;
  const int wid = t >> 6;
  const int idx = blockIdx.x * 1024 + t;
  const int v = (idx < N_NODES) ? cnt[idx] : 0;
  int incl = v;
  #pragma unroll
  for (int off = 1; off < 64; off <<= 1) {
    const int nv = __shfl_up(incl, off, 64);
    if (lane >= off) incl += nv;
  }
  if (lane == 63) wsum[wid] = incl;
  __syncthreads();
  int wpre = 0;
  for (int i = 0; i < wid; ++i) wpre += wsum[i];
  if (idx < N_NODES) offs[idx] = wpre + incl - v;
  if (t == 1023) bsum[blockIdx.x] = wpre + incl;
}

// exclusive scan of the NB_SCAN block sums, in place (single block).
__global__ __launch_bounds__(128) void scan_bsum_kernel(int* __restrict__ bsum) {
  __shared__ int wsum[2];
  const int t = threadIdx.x;
  const int lane = t & 63;
  const int wid = t >> 6;
  const int v = (t < NB_SCAN) ? bsum[t] : 0;
  int incl = v;
  #pragma unroll
  for (int off = 1; off < 64; off <<= 1) {
    const int nv = __shfl_up(incl, off, 64);
    if (lane >= off) incl += nv;
  }
  if (lane == 63) wsum[wid] = incl;
  __syncthreads();
  const int wpre = (wid == 1) ? wsum[0] : 0;
  if (t < NB_SCAN) bsum[t] = wpre + incl - v;
}

__global__ __launch_bounds__(256) void scan_add_kernel(
    int* __restrict__ offs, const int* __restrict__ bsum) {
  const int idx = blockIdx.x * 256 + threadIdx.x;
  if (idx < N_NODES) offs[idx] += bsum[idx >> 10];
  if (idx == 0) offs[N_NODES] = N_EDGES;
}

__global__ __launch_bounds__(256) void scatter_kernel(
    const int* __restrict__ src, const int* __restrict__ dst,
    const int* __restrict__ offs, int* __restrict__ cursor,
    int* __restrict__ srcs) {
  const int i = blockIdx.x * 256 + threadIdx.x;
  if (i < N_EDGES) {
    const int d = dst[i];
    const int pos = offs[d] + atomicAdd(&cursor[d], 1);
    srcs[pos] = src[i];
  }
}

// ---------------------------------------------------------------------------
// GATv2 edge aggregation: wave-per-node. 64 lanes = 8 edge-slots x 8 heads.
// Each edge's 128-B xl row is read coalesced by its 8 head-lanes; 8 edges in
// flight; __shfl_xor reduce over edge-slots; lanes 0-7 write the output row.
// ---------------------------------------------------------------------------
__global__ __launch_bounds__(256) void gat_edge_kernel(
    const float* __restrict__ hin, const float* __restrict__ xl,
    const float* __restrict__ xr, const float* __restrict__ att,
    const float* __restrict__ cbias, const int* __restrict__ offs,
    const int* __restrict__ srcs, float* __restrict__ hout) {
  const int t = threadIdx.x;
  const int lane = t & 63;
  const int node = blockIdx.x * 4 + (t >> 6);   // grid exact: 25000 blocks
  const int head = lane & 7;
  const int e8 = lane >> 3;
  const float4 a4 = *(const float4*)(att + head * 4);
  const float4 r4 = *(const float4*)(xr + (size_t)node * DIM + head * 4);
  const int beg = offs[node];
  const int end = offs[node + 1];
  float den = 0.f, acc0 = 0.f, acc1 = 0.f, acc2 = 0.f, acc3 = 0.f;
  for (int i = beg + e8; i < end; i += 8) {
    const int s = srcs[i];
    const float4 l4 = *(const float4*)(xl + (size_t)s * DIM + head * 4);
    float e0 = l4.x + r4.x; e0 = (e0 > 0.f) ? e0 : 0.2f * e0;
    float e1 = l4.y + r4.y; e1 = (e1 > 0.f) ? e1 : 0.2f * e1;
    float e2 = l4.z + r4.z; e2 = (e2 > 0.f) ? e2 : 0.2f * e2;
    float e3 = l4.w + r4.w; e3 = (e3 > 0.f) ? e3 : 0.2f * e3;
    const float logit = e0 * a4.x + e1 * a4.y + e2 * a4.z + e3 * a4.w;
    const float wgt = __expf(logit);
    den += wgt;
    acc0 += wgt * l4.x; acc1 += wgt * l4.y; acc2 += wgt * l4.z; acc3 += wgt * l4.w;
  }
  #pragma unroll
  for (int m = 8; m <= 32; m <<= 1) {
    den  += __shfl_xor(den, m, 64);
    acc0 += __shfl_xor(acc0, m, 64);
    acc1 += __shfl_xor(acc1, m, 64);
    acc2 += __shfl_xor(acc2, m, 64);
    acc3 += __shfl_xor(acc3, m, 64);
  }
  if (lane < 8) {
    const float inv = 1.f / fmaxf(den, 1e-16f);
    const int o = node * DIM + head * 4;
    const float4 hv = *(const float4*)(hin + o);
    const float4 cb = *(const float4*)(cbias + head * 4);
    float4 out;
    out.x = hv.x + cb.x + acc0 * inv;
    out.y = hv.y + cb.y + acc1 * inv;
    out.z = hv.z + cb.z + acc2 * inv;
    out.w = hv.w + cb.w + acc3 * inv;
    *(float4*)(hout + o) = out;
  }
}

// ---------------------------------------------------------------------------
// pred: out[n][j] = sum_k h[n][k] * w[k][j] + b[j], j < 7
// ---------------------------------------------------------------------------
__global__ __launch_bounds__(256) void pred_kernel(
    const float* __restrict__ h, const float* __restrict__ w,
    const float* __restrict__ b, float* __restrict__ out) {
  __shared__ float wsm[DIM * NUM_CLASS];
  __shared__ float bsm[NUM_CLASS];
  const int t = threadIdx.x;
  if (t < DIM * NUM_CLASS) wsm[t] = w[t];
  if (t < NUM_CLASS) bsm[t] = b[t];
  __syncthreads();
  const int n = blockIdx.x * 256 + t;
  if (n >= N_NODES) return;
  float acc[NUM_CLASS];
  #pragma unroll
  for (int j = 0; j < NUM_CLASS; ++j) acc[j] = bsm[j];
  const float* hr = h + (size_t)n * DIM;
  #pragma unroll
  for (int k = 0; k < DIM; k += 4) {
    const float4 hv = *(const float4*)(hr + k);
    #pragma unroll
    for (int j = 0; j < NUM_CLASS; ++j) {
      acc[j] += hv.x * wsm[(k + 0) * NUM_CLASS + j];
      acc[j] += hv.y * wsm[(k + 1) * NUM_CLASS + j];
      acc[j] += hv.z * wsm[(k + 2) * NUM_CLASS + j];
      acc[j] += hv.w * wsm[(k + 3) * NUM_CLASS + j];
    }
  }
  #pragma unroll
  for (int j = 0; j < NUM_CLASS; ++j) out[(size_t)n * NUM_CLASS + j] = acc[j];
}

// ---------------------------------------------------------------------------
extern "C" void kernel_launch(void* const* d_in, const int* in_sizes, int n_in,
                              void* d_out, int out_size, void* d_ws, size_t ws_size,
                              hipStream_t stream) {
  const float* x       = (const float*)d_in[0];
  const int*   ei      = (const int*)d_in[1];
  const float* w_proj  = (const float*)d_in[2];
  const float* b_proj  = (const float*)d_in[3];
  const float* w_l     = (const float*)d_in[4];
  const float* b_l     = (const float*)d_in[5];
  const float* w_r     = (const float*)d_in[6];
  const float* b_r     = (const float*)d_in[7];
  const float* att     = (const float*)d_in[8];
  const float* cbias   = (const float*)d_in[9];
  const float* w_pred  = (const float*)d_in[10];
  const float* b_pred  = (const float*)d_in[11];

  const int* e_src = ei;
  const int* e_dst = ei + N_EDGES;

  char* wsp = (char*)d_ws;
  size_t off = 0;
  auto take = [&](size_t bytes) -> void* {
    void* p = wsp + off;
    off += (bytes + 255) & ~(size_t)255;
    return p;
  };
  float*  h0    = (float*)take((size_t)N_NODES * DIM * 4);
  float*  h1    = (float*)take((size_t)N_NODES * DIM * 4);
  float*  xl    = (float*)take((size_t)N_NODES * DIM * 4);
  float*  xr    = (float*)take((size_t)N_NODES * DIM * 4);
  int*    offs  = (int*)take((size_t)(N_NODES + 1) * 4);
  int*    cnt   = (int*)take((size_t)N_NODES * 4);
  int*    bsum  = (int*)take((size_t)NB_SCAN * 4);
  int*    srcs  = (int*)take((size_t)N_EDGES * 4);
  bf16x8* wfrag = (bf16x8*)take((size_t)KTILES * 2 * 64 * 16);

  // 1. projection (bf16 MFMA, barrier-free wave-private LDS staging)
  prep_w_kernel<<<KTILES * 2, 64, 0, stream>>>(w_proj, wfrag);
  proj_mfma_kernel<<<(N_WAVES + 3) / 4, 256, 0, stream>>>(x, wfrag, b_proj, h0);

  // 2. CSR build (dst-sorted edge list), reused by both layers
  hipMemsetAsync(cnt, 0, (size_t)N_NODES * 4, stream);
  count_kernel<<<(N_EDGES + 255) / 256, 256, 0, stream>>>(e_dst, cnt);
  scan_local_kernel<<<NB_SCAN, 1024, 0, stream>>>(cnt, offs, bsum);
  scan_bsum_kernel<<<1, 128, 0, stream>>>(bsum);
  scan_add_kernel<<<(N_NODES + 255) / 256, 256, 0, stream>>>(offs, bsum);
  hipMemsetAsync(cnt, 0, (size_t)N_NODES * 4, stream);
  scatter_kernel<<<(N_EDGES + 255) / 256, 256, 0, stream>>>(e_src, e_dst, offs, cnt, srcs);

  // 3. GAT layers
  float* hin = h0;
  float* hout = h1;
  for (int layer = 0; layer < 2; ++layer) {
    lgemm_kernel<<<(N_NODES + 7) / 8, 256, 0, stream>>>(
        hin, w_l + layer * DIM * DIM, b_l + layer * DIM,
        w_r + layer * DIM * DIM, b_r + layer * DIM, xl, xr);
    gat_edge_kernel<<<N_NODES / 4, 256, 0, stream>>>(
        hin, xl, xr, att + layer * HEADS * OUT_C, cbias + layer * DIM,
        offs, srcs, hout);
    float* tmp = hin; hin = hout; hout = tmp;
  }

  // 4. prediction head
  pred_kernel<<<(N_NODES + 255) / 256, 256, 0, stream>>>(hin, w_pred, b_pred, (float*)d_out);
}

// Round 5
// 591.889 us; speedup vs baseline: 2.2919x; 1.0848x over previous
//
#include <hip/hip_runtime.h>

#define N_NODES 100000
#define N_EDGES 3200000
#define IN_C 1433
#define DIM 32
#define HEADS 8
#define OUT_C 4
#define NUM_CLASS 7

#define KTILES 45           // ceil(1433/32); tile 44 is the masked tail
#define N_WAVES 6250        // 100000 / 16 nodes per wave
#define PROJ_BLOCKS 1563    // ceil(6250/4)
#define NB_SCAN 98          // ceil(100000/1024)

typedef __bf16 bf16x8 __attribute__((ext_vector_type(8)));
typedef __bf16 bf16x4 __attribute__((ext_vector_type(4)));
typedef float f32x4 __attribute__((ext_vector_type(4)));

// ---------------------------------------------------------------------------
// init: prep_w fragments (blocks 0..89) + zero cnt & cursor (all blocks).
// wfrag[(kt*2+ch)*64+lane] elem e = w[kt*32+(lane>>4)*8+e][ch*16+(lane&15)].
// ---------------------------------------------------------------------------
__global__ __launch_bounds__(256) void init_kernel(
    const float* __restrict__ w, bf16x8* __restrict__ wfrag,
    int* __restrict__ zbuf /* cnt followed by cursor: 2*N_NODES ints */) {
  const int g = blockIdx.x * 256 + threadIdx.x;
  if (g < 2 * N_NODES) zbuf[g] = 0;
  if (blockIdx.x < KTILES * 2 && threadIdx.x < 64) {
    const int kt = blockIdx.x >> 1;
    const int ch = blockIdx.x & 1;
    const int l = threadIdx.x;
    const int col = ch * 16 + (l & 15);
    const int kbase = kt * 32 + (l >> 4) * 8;
    bf16x8 v;
    #pragma unroll
    for (int e = 0; e < 8; ++e) {
      const int k = kbase + e;
      v[e] = (__bf16)((k < IN_C) ? w[(size_t)k * DIM + col] : 0.f);
    }
    wfrag[(size_t)blockIdx.x * 64 + l] = v;
  }
}

// ---------------------------------------------------------------------------
// proj: h = x @ w + b via bf16 MFMA (wave-private LDS slab, no barriers),
// then a grid-stride degree-count tail (overlaps proj's HBM stream since
// blocks finish staggered). Same staging/swizzle as R4.
// ---------------------------------------------------------------------------
__global__ __launch_bounds__(256) void proj_count_kernel(
    const float* __restrict__ x, const bf16x8* __restrict__ wfrag,
    const float* __restrict__ b, float* __restrict__ h,
    const int* __restrict__ dst, int* __restrict__ cnt) {
  __shared__ float stage[4][16 * 32];
  const int t = threadIdx.x;
  const int lane = t & 63;
  const int wid = t >> 6;
  const int widx = blockIdx.x * 4 + wid;

  if (widx < N_WAVES) {
    const int nodeBase = widx * 16;
    float* slab = stage[wid];

    const int srow = lane >> 5;          // 0..1
    const int scol = lane & 31;
    const float* xbase = x + (size_t)(nodeBase + srow) * IN_C + scol;

    const int frow = lane & 15;
    const int kg = lane >> 4;            // 0..3
    const int sw = frow & 7;
    const int rd0 = frow * 32 + (((2 * kg) ^ sw) << 2);
    const int rd1 = frow * 32 + (((2 * kg + 1) ^ sw) << 2);
    const bf16x8* wp = wfrag + lane;

    f32x4 acc0 = {0.f, 0.f, 0.f, 0.f};
    f32x4 acc1 = {0.f, 0.f, 0.f, 0.f};

    float cur[8];
    #pragma unroll
    for (int i = 0; i < 8; ++i) cur[i] = xbase[(size_t)(2 * i) * IN_C];

    for (int kt = 0; kt < KTILES; ++kt) {
      #pragma unroll
      for (int i = 0; i < 8; ++i) {
        const int row = 2 * i + srow;
        const int p = (scol >> 2) ^ (row & 7);
        slab[row * 32 + (p << 2) + (scol & 3)] = cur[i];
      }
      if (kt + 1 < KTILES) {
        const int gk = (kt + 1) * 32 + scol;
        const float* xp = xbase + (size_t)(kt + 1) * 32;
        const bool ok = gk < IN_C;
        #pragma unroll
        for (int i = 0; i < 8; ++i)
          cur[i] = ok ? xp[(size_t)(2 * i) * IN_C] : 0.f;
      }
      const f32x4 lo = *(const f32x4*)(slab + rd0);
      const f32x4 hi = *(const f32x4*)(slab + rd1);
      bf16x8 af;
      af[0] = (__bf16)lo[0]; af[1] = (__bf16)lo[1];
      af[2] = (__bf16)lo[2]; af[3] = (__bf16)lo[3];
      af[4] = (__bf16)hi[0]; af[5] = (__bf16)hi[1];
      af[6] = (__bf16)hi[2]; af[7] = (__bf16)hi[3];
      const bf16x8 b0 = wp[(kt * 2 + 0) * 64];
      const bf16x8 b1 = wp[(kt * 2 + 1) * 64];
      acc0 = __builtin_amdgcn_mfma_f32_16x16x32_bf16(af, b0, acc0, 0, 0, 0);
      acc1 = __builtin_amdgcn_mfma_f32_16x16x32_bf16(af, b1, acc1, 0, 0, 0);
    }

    const float bc0 = b[frow];
    const float bc1 = b[frow + 16];
    #pragma unroll
    for (int rg = 0; rg < 4; ++rg) {
      const size_t o = (size_t)(nodeBase + kg * 4 + rg) * DIM + frow;
      h[o] = acc0[rg] + bc0;
      h[o + 16] = acc1[rg] + bc1;
    }
  }

  // degree count tail (all threads, incl. the 2 idle tail waves)
  for (int e = blockIdx.x * 256 + t; e < N_EDGES; e += PROJ_BLOCKS * 256)
    atomicAdd(&cnt[dst[e]], 1);
}

// ---------------------------------------------------------------------------
// scan_local: block-local exclusive scan of 1024 counts; block total -> bsum.
// ---------------------------------------------------------------------------
__global__ __launch_bounds__(1024) void scan_local_kernel(
    const int* __restrict__ cnt, int* __restrict__ offs, int* __restrict__ bsum) {
  __shared__ int wsum[16];
  const int t = threadIdx.x;
  const int lane = t & 63;
  const int wid = t >> 6;
  const int idx = blockIdx.x * 1024 + t;
  const int v = (idx < N_NODES) ? cnt[idx] : 0;
  int incl = v;
  #pragma unroll
  for (int off = 1; off < 64; off <<= 1) {
    const int nv = __shfl_up(incl, off, 64);
    if (lane >= off) incl += nv;
  }
  if (lane == 63) wsum[wid] = incl;
  __syncthreads();
  int wpre = 0;
  for (int i = 0; i < wid; ++i) wpre += wsum[i];
  if (idx < N_NODES) offs[idx] = wpre + incl - v;
  if (t == 1023) bsum[blockIdx.x] = wpre + incl;
}

// ---------------------------------------------------------------------------
// scan_add: each block re-reduces bsum[0..k-1] (k = blockIdx>>2, <=97) and
// adds the base to its 256 offs entries (256-blocks never straddle a 1024
// scan_local block, so one base per block).
// ---------------------------------------------------------------------------
__global__ __launch_bounds__(256) void scan_add_kernel(
    int* __restrict__ offs, const int* __restrict__ bsum) {
  __shared__ int wsum[4];
  const int t = threadIdx.x;
  const int lane = t & 63;
  const int wid = t >> 6;
  const int k = blockIdx.x >> 2;
  int v = (t < k) ? bsum[t] : 0;
  #pragma unroll
  for (int m = 1; m < 64; m <<= 1) v += __shfl_xor(v, m, 64);
  if (lane == 0) wsum[wid] = v;
  __syncthreads();
  const int base = wsum[0] + wsum[1] + wsum[2] + wsum[3];
  const int idx = blockIdx.x * 256 + t;
  if (idx < N_NODES) offs[idx] += base;
  if (idx == 0) offs[N_NODES] = N_EDGES;
}

// ---------------------------------------------------------------------------
// scatter (blocks 0..12499) || lgemm layer (blocks 12500..24999).
// lgemm: xl -> bf16 (halves the edge-gather bytes), xr -> fp32.
// ---------------------------------------------------------------------------
__global__ __launch_bounds__(256) void scatter_lgemm_kernel(
    const int* __restrict__ src, const int* __restrict__ dst,
    const int* __restrict__ offs, int* __restrict__ cursor,
    int* __restrict__ srcs,
    const float* __restrict__ h,
    const float* __restrict__ wl, const float* __restrict__ bl,
    const float* __restrict__ wr, const float* __restrict__ br,
    __bf16* __restrict__ xlb, float* __restrict__ xr) {
  const int t = threadIdx.x;
  if (blockIdx.x < 12500) {
    const int i = blockIdx.x * 256 + t;
    if (i < N_EDGES) {
      const int d = dst[i];
      const int pos = offs[d] + atomicAdd(&cursor[d], 1);
      srcs[pos] = src[i];
    }
  } else {
    __shared__ float wls[DIM * DIM];
    __shared__ float wrs[DIM * DIM];
    for (int i = t; i < DIM * DIM; i += 256) { wls[i] = wl[i]; wrs[i] = wr[i]; }
    __syncthreads();
    const int node = (blockIdx.x - 12500) * 8 + (t >> 5);
    const int col = t & 31;
    const float* hrow = h + (size_t)node * DIM;
    float al = bl[col], ar = br[col];
    #pragma unroll
    for (int k = 0; k < DIM; ++k) {
      const float hv = hrow[k];
      al += hv * wls[k * DIM + col];
      ar += hv * wrs[k * DIM + col];
    }
    xlb[(size_t)node * DIM + col] = (__bf16)al;
    xr[(size_t)node * DIM + col] = ar;
  }
}

// standalone lgemm for layer 1
__global__ __launch_bounds__(256) void lgemm_kernel(
    const float* __restrict__ h,
    const float* __restrict__ wl, const float* __restrict__ bl,
    const float* __restrict__ wr, const float* __restrict__ br,
    __bf16* __restrict__ xlb, float* __restrict__ xr) {
  __shared__ float wls[DIM * DIM];
  __shared__ float wrs[DIM * DIM];
  const int t = threadIdx.x;
  for (int i = t; i < DIM * DIM; i += 256) { wls[i] = wl[i]; wrs[i] = wr[i]; }
  __syncthreads();
  const int node = blockIdx.x * 8 + (t >> 5);
  const int col = t & 31;
  if (node >= N_NODES) return;
  const float* hrow = h + (size_t)node * DIM;
  float al = bl[col], ar = br[col];
  #pragma unroll
  for (int k = 0; k < DIM; ++k) {
    const float hv = hrow[k];
    al += hv * wls[k * DIM + col];
    ar += hv * wrs[k * DIM + col];
  }
  xlb[(size_t)node * DIM + col] = (__bf16)al;
  xr[(size_t)node * DIM + col] = ar;
}

// ---------------------------------------------------------------------------
// GATv2 edge aggregation: wave-per-node, 8 edge-slots x 8 heads, bf16 xl.
// Layer 0 variant: writes hout (fp32).
// ---------------------------------------------------------------------------
__global__ __launch_bounds__(256) void gat_edge_kernel(
    const float* __restrict__ hin, const __bf16* __restrict__ xlb,
    const float* __restrict__ xr, const float* __restrict__ att,
    const float* __restrict__ cbias, const int* __restrict__ offs,
    const int* __restrict__ srcs, float* __restrict__ hout) {
  const int t = threadIdx.x;
  const int lane = t & 63;
  const int node = blockIdx.x * 4 + (t >> 6);
  const int head = lane & 7;
  const int e8 = lane >> 3;
  const float4 a4 = *(const float4*)(att + head * 4);
  const float4 r4 = *(const float4*)(xr + (size_t)node * DIM + head * 4);
  const int beg = offs[node];
  const int end = offs[node + 1];
  float den = 0.f, acc0 = 0.f, acc1 = 0.f, acc2 = 0.f, acc3 = 0.f;
  for (int i = beg + e8; i < end; i += 8) {
    const int s = srcs[i];
    const bf16x4 lb = *(const bf16x4*)(xlb + ((size_t)s << 5) + (head << 2));
    const float l0 = (float)lb[0], l1 = (float)lb[1], l2 = (float)lb[2], l3 = (float)lb[3];
    float e0 = l0 + r4.x; e0 = (e0 > 0.f) ? e0 : 0.2f * e0;
    float e1 = l1 + r4.y; e1 = (e1 > 0.f) ? e1 : 0.2f * e1;
    float e2 = l2 + r4.z; e2 = (e2 > 0.f) ? e2 : 0.2f * e2;
    float e3 = l3 + r4.w; e3 = (e3 > 0.f) ? e3 : 0.2f * e3;
    const float logit = e0 * a4.x + e1 * a4.y + e2 * a4.z + e3 * a4.w;
    const float wgt = __expf(logit);
    den += wgt;
    acc0 += wgt * l0; acc1 += wgt * l1; acc2 += wgt * l2; acc3 += wgt * l3;
  }
  #pragma unroll
  for (int m = 8; m <= 32; m <<= 1) {
    den  += __shfl_xor(den, m, 64);
    acc0 += __shfl_xor(acc0, m, 64);
    acc1 += __shfl_xor(acc1, m, 64);
    acc2 += __shfl_xor(acc2, m, 64);
    acc3 += __shfl_xor(acc3, m, 64);
  }
  if (lane < 8) {
    const float inv = 1.f / fmaxf(den, 1e-16f);
    const int o = node * DIM + head * 4;
    const float4 hv = *(const float4*)(hin + o);
    const float4 cb = *(const float4*)(cbias + head * 4);
    float4 out;
    out.x = hv.x + cb.x + acc0 * inv;
    out.y = hv.y + cb.y + acc1 * inv;
    out.z = hv.z + cb.z + acc2 * inv;
    out.w = hv.w + cb.w + acc3 * inv;
    *(float4*)(hout + o) = out;
  }
}

// Layer 1 variant: h2 never materialized; pred fused, writes d_out [N,7].
__global__ __launch_bounds__(256) void gat_edge_pred_kernel(
    const float* __restrict__ hin, const __bf16* __restrict__ xlb,
    const float* __restrict__ xr, const float* __restrict__ att,
    const float* __restrict__ cbias, const int* __restrict__ offs,
    const int* __restrict__ srcs,
    const float* __restrict__ wp, const float* __restrict__ bp,
    float* __restrict__ out) {
  const int t = threadIdx.x;
  const int lane = t & 63;
  const int node = blockIdx.x * 4 + (t >> 6);
  const int head = lane & 7;
  const int e8 = lane >> 3;
  const float4 a4 = *(const float4*)(att + head * 4);
  const float4 r4 = *(const float4*)(xr + (size_t)node * DIM + head * 4);
  const int beg = offs[node];
  const int end = offs[node + 1];
  float den = 0.f, acc0 = 0.f, acc1 = 0.f, acc2 = 0.f, acc3 = 0.f;
  for (int i = beg + e8; i < end; i += 8) {
    const int s = srcs[i];
    const bf16x4 lb = *(const bf16x4*)(xlb + ((size_t)s << 5) + (head << 2));
    const float l0 = (float)lb[0], l1 = (float)lb[1], l2 = (float)lb[2], l3 = (float)lb[3];
    float e0 = l0 + r4.x; e0 = (e0 > 0.f) ? e0 : 0.2f * e0;
    float e1 = l1 + r4.y; e1 = (e1 > 0.f) ? e1 : 0.2f * e1;
    float e2 = l2 + r4.z; e2 = (e2 > 0.f) ? e2 : 0.2f * e2;
    float e3 = l3 + r4.w; e3 = (e3 > 0.f) ? e3 : 0.2f * e3;
    const float logit = e0 * a4.x + e1 * a4.y + e2 * a4.z + e3 * a4.w;
    const float wgt = __expf(logit);
    den += wgt;
    acc0 += wgt * l0; acc1 += wgt * l1; acc2 += wgt * l2; acc3 += wgt * l3;
  }
  #pragma unroll
  for (int m = 8; m <= 32; m <<= 1) {   // all 64 lanes end with head totals
    den  += __shfl_xor(den, m, 64);
    acc0 += __shfl_xor(acc0, m, 64);
    acc1 += __shfl_xor(acc1, m, 64);
    acc2 += __shfl_xor(acc2, m, 64);
    acc3 += __shfl_xor(acc3, m, 64);
  }
  // final h row element for (node, head): computed redundantly in all lanes
  const float inv = 1.f / fmaxf(den, 1e-16f);
  const int o = node * DIM + head * 4;
  const float4 hv = *(const float4*)(hin + o);
  const float4 cb = *(const float4*)(cbias + head * 4);
  const float o0 = hv.x + cb.x + acc0 * inv;
  const float o1 = hv.y + cb.y + acc1 * inv;
  const float o2 = hv.z + cb.z + acc2 * inv;
  const float o3 = hv.w + cb.w + acc3 * inv;
  // pred partials for this head's 4 dims
  float pj[NUM_CLASS];
  const float* wr0 = wp + (head * 4 + 0) * NUM_CLASS;
  const float* wr1 = wp + (head * 4 + 1) * NUM_CLASS;
  const float* wr2 = wp + (head * 4 + 2) * NUM_CLASS;
  const float* wr3 = wp + (head * 4 + 3) * NUM_CLASS;
  #pragma unroll
  for (int j = 0; j < NUM_CLASS; ++j)
    pj[j] = o0 * wr0[j] + o1 * wr1[j] + o2 * wr2[j] + o3 * wr3[j];
  #pragma unroll
  for (int m = 1; m <= 4; m <<= 1) {    // reduce across 8 heads in-group
    #pragma unroll
    for (int j = 0; j < NUM_CLASS; ++j) pj[j] += __shfl_xor(pj[j], m, 64);
  }
  if (lane == 0) {
    #pragma unroll
    for (int j = 0; j < NUM_CLASS; ++j)
      out[(size_t)node * NUM_CLASS + j] = pj[j] + bp[j];
  }
}

// ---------------------------------------------------------------------------
extern "C" void kernel_launch(void* const* d_in, const int* in_sizes, int n_in,
                              void* d_out, int out_size, void* d_ws, size_t ws_size,
                              hipStream_t stream) {
  const float* x       = (const float*)d_in[0];
  const int*   ei      = (const int*)d_in[1];
  const float* w_proj  = (const float*)d_in[2];
  const float* b_proj  = (const float*)d_in[3];
  const float* w_l     = (const float*)d_in[4];
  const float* b_l     = (const float*)d_in[5];
  const float* w_r     = (const float*)d_in[6];
  const float* b_r     = (const float*)d_in[7];
  const float* att     = (const float*)d_in[8];
  const float* cbias   = (const float*)d_in[9];
  const float* w_pred  = (const float*)d_in[10];
  const float* b_pred  = (const float*)d_in[11];

  const int* e_src = ei;
  const int* e_dst = ei + N_EDGES;

  char* wsp = (char*)d_ws;
  size_t off = 0;
  auto take = [&](size_t bytes) -> void* {
    void* p = wsp + off;
    off += (bytes + 255) & ~(size_t)255;
    return p;
  };
  float*  h0    = (float*)take((size_t)N_NODES * DIM * 4);
  float*  h1    = (float*)take((size_t)N_NODES * DIM * 4);
  __bf16* xlb   = (__bf16*)take((size_t)N_NODES * DIM * 2);
  float*  xr    = (float*)take((size_t)N_NODES * DIM * 4);
  int*    offs  = (int*)take((size_t)(N_NODES + 1) * 4);
  int*    zbuf  = (int*)take((size_t)2 * N_NODES * 4);  // cnt | cursor
  int*    bsum  = (int*)take((size_t)NB_SCAN * 4);
  int*    srcs  = (int*)take((size_t)N_EDGES * 4);
  bf16x8* wfrag = (bf16x8*)take((size_t)KTILES * 2 * 64 * 16);
  int* cnt = zbuf;
  int* cursor = zbuf + N_NODES;

  // 1. init: wfrag pack + zero cnt/cursor
  init_kernel<<<(2 * N_NODES + 255) / 256, 256, 0, stream>>>(w_proj, wfrag, zbuf);
  // 2. proj + degree count
  proj_count_kernel<<<PROJ_BLOCKS, 256, 0, stream>>>(x, wfrag, b_proj, h0, e_dst, cnt);
  // 3-4. scan
  scan_local_kernel<<<NB_SCAN, 1024, 0, stream>>>(cnt, offs, bsum);
  scan_add_kernel<<<(N_NODES + 255) / 256, 256, 0, stream>>>(offs, bsum);
  // 5. scatter || lgemm layer 0
  scatter_lgemm_kernel<<<25000, 256, 0, stream>>>(
      e_src, e_dst, offs, cursor, srcs,
      h0, w_l, b_l, w_r, b_r, xlb, xr);
  // 6. gat layer 0 -> h1
  gat_edge_kernel<<<N_NODES / 4, 256, 0, stream>>>(
      h0, xlb, xr, att, cbias, offs, srcs, h1);
  // 7. lgemm layer 1
  lgemm_kernel<<<(N_NODES + 7) / 8, 256, 0, stream>>>(
      h1, w_l + DIM * DIM, b_l + DIM, w_r + DIM * DIM, b_r + DIM, xlb, xr);
  // 8. gat layer 1 + pred -> d_out
  gat_edge_pred_kernel<<<N_NODES / 4, 256, 0, stream>>>(
      h1, xlb, xr, att + HEADS * OUT_C, cbias + DIM, offs, srcs,
      w_pred, b_pred, (float*)d_out);
}

// Round 6
// 538.597 us; speedup vs baseline: 2.5186x; 1.0989x over previous
//
#include <hip/hip_runtime.h>

#define N_NODES 100000
#define N_EDGES 3200000
#define IN_C 1433
#define DIM 32
#define HEADS 8
#define OUT_C 4
#define NUM_CLASS 7

#define KTILES 45           // ceil(1433/32); tile 44 is the masked tail
#define N_WAVES 6250        // 100000 / 16 nodes per wave
#define PROJ_BLOCKS 1563    // ceil(6250/4)
#define NB_SCAN 98          // ceil(100000/1024)

typedef __bf16 bf16x8 __attribute__((ext_vector_type(8)));
typedef __bf16 bf16x4 __attribute__((ext_vector_type(4)));
typedef float f32x4 __attribute__((ext_vector_type(4)));

// ---------------------------------------------------------------------------
// init: zero degree counters (all blocks) + pack w into per-lane MFMA
// B-fragments (blocks 0..89). wfrag[(kt*2+ch)*64+lane] elem e =
// w[kt*32+(lane>>4)*8+e][ch*16+(lane&15)], zero-padded past k=1433.
// ---------------------------------------------------------------------------
__global__ __launch_bounds__(256) void init_kernel(
    const float* __restrict__ w, bf16x8* __restrict__ wfrag,
    int* __restrict__ cnt) {
  const int g = blockIdx.x * 256 + threadIdx.x;
  if (g < N_NODES) cnt[g] = 0;
  if (blockIdx.x < KTILES * 2 && threadIdx.x < 64) {
    const int kt = blockIdx.x >> 1;
    const int ch = blockIdx.x & 1;
    const int l = threadIdx.x;
    const int col = ch * 16 + (l & 15);
    const int kbase = kt * 32 + (l >> 4) * 8;
    bf16x8 v;
    #pragma unroll
    for (int e = 0; e < 8; ++e) {
      const int k = kbase + e;
      v[e] = (__bf16)((k < IN_C) ? w[(size_t)k * DIM + col] : 0.f);
    }
    wfrag[(size_t)blockIdx.x * 64 + l] = v;
  }
}

// ---------------------------------------------------------------------------
// proj: h = x @ w + b via bf16 MFMA, wave-private LDS slab (no barriers).
// Staging: 2 x float4 global loads + 2 x swizzled ds_write_b128 per tile
// (tail tile scalar-masked). Then grid-stride degree-count tail that also
// records each edge's within-bucket rank (makes scatter atomic-free).
// ---------------------------------------------------------------------------
__global__ __launch_bounds__(256) void proj_count_kernel(
    const float* __restrict__ x, const bf16x8* __restrict__ wfrag,
    const float* __restrict__ b, float* __restrict__ h,
    const int* __restrict__ dst, int* __restrict__ cnt,
    int* __restrict__ rank) {
  __shared__ float stage[4][16 * 32];
  const int t = threadIdx.x;
  const int lane = t & 63;
  const int wid = t >> 6;
  const int widx = blockIdx.x * 4 + wid;

  if (widx < N_WAVES) {
    const int nodeBase = widx * 16;
    float* slab = stage[wid];

    // float4 staging map: lane -> (row qrow, granule qcol); instr i adds 8 rows
    const int qrow = lane >> 3;          // 0..7
    const int qcol = lane & 7;           // granule (4 floats)
    const float* xq = x + (size_t)(nodeBase + qrow) * IN_C + qcol * 4;

    // fragment map
    const int frow = lane & 15;
    const int kg = lane >> 4;            // 0..3
    const int sw = frow & 7;
    const int rd0 = frow * 32 + (((2 * kg) ^ sw) << 2);
    const int rd1 = frow * 32 + (((2 * kg + 1) ^ sw) << 2);
    const bf16x8* wp = wfrag + lane;

    f32x4 acc0 = {0.f, 0.f, 0.f, 0.f};
    f32x4 acc1 = {0.f, 0.f, 0.f, 0.f};

    f32x4 cur0 = *(const f32x4*)(xq);
    f32x4 cur1 = *(const f32x4*)(xq + (size_t)8 * IN_C);

    for (int kt = 0; kt < KTILES - 1; ++kt) {
      // stage cur -> LDS (16B-granule swizzle)
      {
        const int g0 = qcol ^ (qrow & 7);
        *(f32x4*)(slab + qrow * 32 + (g0 << 2)) = cur0;
        const int r1 = qrow + 8;
        const int g1 = qcol ^ (r1 & 7);
        *(f32x4*)(slab + r1 * 32 + (g1 << 2)) = cur1;
      }
      // prefetch next full tile
      if (kt + 1 < KTILES - 1) {
        const float* xp = xq + (size_t)(kt + 1) * 32;
        cur0 = *(const f32x4*)(xp);
        cur1 = *(const f32x4*)(xp + (size_t)8 * IN_C);
      }
      const f32x4 lo = *(const f32x4*)(slab + rd0);
      const f32x4 hi = *(const f32x4*)(slab + rd1);
      bf16x8 af;
      af[0] = (__bf16)lo[0]; af[1] = (__bf16)lo[1];
      af[2] = (__bf16)lo[2]; af[3] = (__bf16)lo[3];
      af[4] = (__bf16)hi[0]; af[5] = (__bf16)hi[1];
      af[6] = (__bf16)hi[2]; af[7] = (__bf16)hi[3];
      const bf16x8 b0 = wp[(kt * 2 + 0) * 64];
      const bf16x8 b1 = wp[(kt * 2 + 1) * 64];
      acc0 = __builtin_amdgcn_mfma_f32_16x16x32_bf16(af, b0, acc0, 0, 0, 0);
      acc1 = __builtin_amdgcn_mfma_f32_16x16x32_bf16(af, b1, acc1, 0, 0, 0);
    }
    {  // tail tile kt=44: scalar masked loads, dword swizzled stores
      const int srow = lane >> 5;        // 0..1
      const int scol = lane & 31;
      const bool ok = (1408 + scol) < IN_C;
      const float* xt = x + (size_t)(nodeBase + srow) * IN_C + 1408 + scol;
      #pragma unroll
      for (int i = 0; i < 8; ++i) {
        const int row = 2 * i + srow;
        const float v = ok ? xt[(size_t)(2 * i) * IN_C] : 0.f;
        const int p = (scol >> 2) ^ (row & 7);
        slab[row * 32 + (p << 2) + (scol & 3)] = v;
      }
      const f32x4 lo = *(const f32x4*)(slab + rd0);
      const f32x4 hi = *(const f32x4*)(slab + rd1);
      bf16x8 af;
      af[0] = (__bf16)lo[0]; af[1] = (__bf16)lo[1];
      af[2] = (__bf16)lo[2]; af[3] = (__bf16)lo[3];
      af[4] = (__bf16)hi[0]; af[5] = (__bf16)hi[1];
      af[6] = (__bf16)hi[2]; af[7] = (__bf16)hi[3];
      const bf16x8 b0 = wp[((KTILES - 1) * 2 + 0) * 64];
      const bf16x8 b1 = wp[((KTILES - 1) * 2 + 1) * 64];
      acc0 = __builtin_amdgcn_mfma_f32_16x16x32_bf16(af, b0, acc0, 0, 0, 0);
      acc1 = __builtin_amdgcn_mfma_f32_16x16x32_bf16(af, b1, acc1, 0, 0, 0);
    }

    const float bc0 = b[frow];
    const float bc1 = b[frow + 16];
    #pragma unroll
    for (int rg = 0; rg < 4; ++rg) {
      const size_t o = (size_t)(nodeBase + kg * 4 + rg) * DIM + frow;
      h[o] = acc0[rg] + bc0;
      h[o + 16] = acc1[rg] + bc1;
    }
  }

  // degree count + rank capture (atomics hide under proj's HBM stream)
  for (int e = blockIdx.x * 256 + t; e < N_EDGES; e += PROJ_BLOCKS * 256)
    rank[e] = atomicAdd(&cnt[dst[e]], 1);
}

// ---------------------------------------------------------------------------
// scan_local: block-local exclusive scan of 1024 counts; block total -> bsum.
// ---------------------------------------------------------------------------
__global__ __launch_bounds__(1024) void scan_local_kernel(
    const int* __restrict__ cnt, int* __restrict__ offs, int* __restrict__ bsum) {
  __shared__ int wsum[16];
  const int t = threadIdx.x;
  const int lane = t & 63;
  const int wid = t >> 6;
  const int idx = blockIdx.x * 1024 + t;
  const int v = (idx < N_NODES) ? cnt[idx] : 0;
  int incl = v;
  #pragma unroll
  for (int off = 1; off < 64; off <<= 1) {
    const int nv = __shfl_up(incl, off, 64);
    if (lane >= off) incl += nv;
  }
  if (lane == 63) wsum[wid] = incl;
  __syncthreads();
  int wpre = 0;
  for (int i = 0; i < wid; ++i) wpre += wsum[i];
  if (idx < N_NODES) offs[idx] = wpre + incl - v;
  if (t == 1023) bsum[blockIdx.x] = wpre + incl;
}

// ---------------------------------------------------------------------------
// scan_add: block re-reduces bsum prefix (k = blockIdx>>2 <= 97) and adds it.
// ---------------------------------------------------------------------------
__global__ __launch_bounds__(256) void scan_add_kernel(
    int* __restrict__ offs, const int* __restrict__ bsum) {
  __shared__ int wsum[4];
  const int t = threadIdx.x;
  const int lane = t & 63;
  const int wid = t >> 6;
  const int k = blockIdx.x >> 2;
  int v = (t < k) ? bsum[t] : 0;
  #pragma unroll
  for (int m = 1; m < 64; m <<= 1) v += __shfl_xor(v, m, 64);
  if (lane == 0) wsum[wid] = v;
  __syncthreads();
  const int base = wsum[0] + wsum[1] + wsum[2] + wsum[3];
  const int idx = blockIdx.x * 256 + t;
  if (idx < N_NODES) offs[idx] += base;
  if (idx == 0) offs[N_NODES] = N_EDGES;
}

// ---------------------------------------------------------------------------
// scatter (atomic-free, blocks 0..12499) || lgemm layer 0 (blocks 12500..).
// ---------------------------------------------------------------------------
__global__ __launch_bounds__(256) void scatter_lgemm_kernel(
    const int* __restrict__ src, const int* __restrict__ dst,
    const int* __restrict__ offs, const int* __restrict__ rank,
    int* __restrict__ srcs,
    const float* __restrict__ h,
    const float* __restrict__ wl, const float* __restrict__ bl,
    const float* __restrict__ wr, const float* __restrict__ br,
    __bf16* __restrict__ xlb, float* __restrict__ xr) {
  const int t = threadIdx.x;
  if (blockIdx.x < 12500) {
    const int i = blockIdx.x * 256 + t;
    if (i < N_EDGES) {
      const int d = dst[i];
      srcs[offs[d] + rank[i]] = src[i];
    }
  } else {
    __shared__ float wls[DIM * DIM];
    __shared__ float wrs[DIM * DIM];
    for (int i = t; i < DIM * DIM; i += 256) { wls[i] = wl[i]; wrs[i] = wr[i]; }
    __syncthreads();
    const int node = (blockIdx.x - 12500) * 8 + (t >> 5);
    const int col = t & 31;
    const float* hrow = h + (size_t)node * DIM;
    float al = bl[col], ar = br[col];
    #pragma unroll
    for (int k = 0; k < DIM; ++k) {
      const float hv = hrow[k];
      al += hv * wls[k * DIM + col];
      ar += hv * wrs[k * DIM + col];
    }
    xlb[(size_t)node * DIM + col] = (__bf16)al;
    xr[(size_t)node * DIM + col] = ar;
  }
}

// ---------------------------------------------------------------------------
// gat layer 0 + fused lgemm layer 1. Wave-per-node, 8 edge-slots x 8 heads.
// After head-reduce, h1 row lives in lanes 0-7; shfl-broadcast + LDS weights
// compute layer-1 xl (lanes 0-31, bf16) and xr (lanes 32-63, fp32) directly.
// Writes xlB/xrB (separate buffers: xlA/xrA still being gathered by peers).
// ---------------------------------------------------------------------------
__global__ __launch_bounds__(256) void gat_lgemm_kernel(
    const float* __restrict__ hin, const __bf16* __restrict__ xlb,
    const float* __restrict__ xr, const float* __restrict__ att,
    const float* __restrict__ cbias, const int* __restrict__ offs,
    const int* __restrict__ srcs, float* __restrict__ hout,
    const float* __restrict__ wl1, const float* __restrict__ bl1,
    const float* __restrict__ wr1, const float* __restrict__ br1,
    __bf16* __restrict__ xlbB, float* __restrict__ xrB) {
  __shared__ float wls[DIM * DIM];
  __shared__ float wrs[DIM * DIM];
  const int t = threadIdx.x;
  for (int i = t; i < DIM * DIM; i += 256) { wls[i] = wl1[i]; wrs[i] = wr1[i]; }
  __syncthreads();

  const int lane = t & 63;
  const int node = blockIdx.x * 4 + (t >> 6);
  const int head = lane & 7;
  const int e8 = lane >> 3;
  const float4 a4 = *(const float4*)(att + head * 4);
  const float4 r4 = *(const float4*)(xr + (size_t)node * DIM + head * 4);
  const int beg = offs[node];
  const int end = offs[node + 1];
  float den = 0.f, acc0 = 0.f, acc1 = 0.f, acc2 = 0.f, acc3 = 0.f;
  for (int i = beg + e8; i < end; i += 8) {
    const int s = srcs[i];
    const bf16x4 lb = *(const bf16x4*)(xlb + ((size_t)s << 5) + (head << 2));
    const float l0 = (float)lb[0], l1 = (float)lb[1], l2 = (float)lb[2], l3 = (float)lb[3];
    float e0 = l0 + r4.x; e0 = (e0 > 0.f) ? e0 : 0.2f * e0;
    float e1 = l1 + r4.y; e1 = (e1 > 0.f) ? e1 : 0.2f * e1;
    float e2 = l2 + r4.z; e2 = (e2 > 0.f) ? e2 : 0.2f * e2;
    float e3 = l3 + r4.w; e3 = (e3 > 0.f) ? e3 : 0.2f * e3;
    const float logit = e0 * a4.x + e1 * a4.y + e2 * a4.z + e3 * a4.w;
    const float wgt = __expf(logit);
    den += wgt;
    acc0 += wgt * l0; acc1 += wgt * l1; acc2 += wgt * l2; acc3 += wgt * l3;
  }
  #pragma unroll
  for (int m = 8; m <= 32; m <<= 1) {
    den  += __shfl_xor(den, m, 64);
    acc0 += __shfl_xor(acc0, m, 64);
    acc1 += __shfl_xor(acc1, m, 64);
    acc2 += __shfl_xor(acc2, m, 64);
    acc3 += __shfl_xor(acc3, m, 64);
  }
  // h1 row element (node, head*4+c), computed in all lanes
  const float inv = 1.f / fmaxf(den, 1e-16f);
  const int o = node * DIM + head * 4;
  const float4 hv = *(const float4*)(hin + o);
  const float4 cb = *(const float4*)(cbias + head * 4);
  const float o0 = hv.x + cb.x + acc0 * inv;
  const float o1 = hv.y + cb.y + acc1 * inv;
  const float o2 = hv.z + cb.z + acc2 * inv;
  const float o3 = hv.w + cb.w + acc3 * inv;
  if (lane < 8) {
    float4 outv; outv.x = o0; outv.y = o1; outv.z = o2; outv.w = o3;
    *(float4*)(hout + o) = outv;
  }
  // fused lgemm layer 1: lanes 0-31 -> xl (bf16), lanes 32-63 -> xr (fp32)
  const int col = lane & 31;
  const float* wsel = (lane < 32) ? wls : wrs;
  float a = (lane < 32) ? bl1[col] : br1[col];
  #pragma unroll
  for (int k = 0; k < DIM; ++k) {
    const float src = (k & 3) == 0 ? o0 : (k & 3) == 1 ? o1 : (k & 3) == 2 ? o2 : o3;
    const float hk = __shfl(src, k >> 2, 64);
    a += hk * wsel[k * DIM + col];
  }
  const size_t xo = ((size_t)node << 5) + col;
  if (lane < 32) xlbB[xo] = (__bf16)a;
  else           xrB[xo] = a;
}

// ---------------------------------------------------------------------------
// gat layer 1 + fused pred -> d_out [N, 7]; h2 never materialized.
// ---------------------------------------------------------------------------
__global__ __launch_bounds__(256) void gat_edge_pred_kernel(
    const float* __restrict__ hin, const __bf16* __restrict__ xlb,
    const float* __restrict__ xr, const float* __restrict__ att,
    const float* __restrict__ cbias, const int* __restrict__ offs,
    const int* __restrict__ srcs,
    const float* __restrict__ wp, const float* __restrict__ bp,
    float* __restrict__ out) {
  const int t = threadIdx.x;
  const int lane = t & 63;
  const int node = blockIdx.x * 4 + (t >> 6);
  const int head = lane & 7;
  const int e8 = lane >> 3;
  const float4 a4 = *(const float4*)(att + head * 4);
  const float4 r4 = *(const float4*)(xr + (size_t)node * DIM + head * 4);
  const int beg = offs[node];
  const int end = offs[node + 1];
  float den = 0.f, acc0 = 0.f, acc1 = 0.f, acc2 = 0.f, acc3 = 0.f;
  for (int i = beg + e8; i < end; i += 8) {
    const int s = srcs[i];
    const bf16x4 lb = *(const bf16x4*)(xlb + ((size_t)s << 5) + (head << 2));
    const float l0 = (float)lb[0], l1 = (float)lb[1], l2 = (float)lb[2], l3 = (float)lb[3];
    float e0 = l0 + r4.x; e0 = (e0 > 0.f) ? e0 : 0.2f * e0;
    float e1 = l1 + r4.y; e1 = (e1 > 0.f) ? e1 : 0.2f * e1;
    float e2 = l2 + r4.z; e2 = (e2 > 0.f) ? e2 : 0.2f * e2;
    float e3 = l3 + r4.w; e3 = (e3 > 0.f) ? e3 : 0.2f * e3;
    const float logit = e0 * a4.x + e1 * a4.y + e2 * a4.z + e3 * a4.w;
    const float wgt = __expf(logit);
    den += wgt;
    acc0 += wgt * l0; acc1 += wgt * l1; acc2 += wgt * l2; acc3 += wgt * l3;
  }
  #pragma unroll
  for (int m = 8; m <= 32; m <<= 1) {
    den  += __shfl_xor(den, m, 64);
    acc0 += __shfl_xor(acc0, m, 64);
    acc1 += __shfl_xor(acc1, m, 64);
    acc2 += __shfl_xor(acc2, m, 64);
    acc3 += __shfl_xor(acc3, m, 64);
  }
  const float inv = 1.f / fmaxf(den, 1e-16f);
  const int o = node * DIM + head * 4;
  const float4 hv = *(const float4*)(hin + o);
  const float4 cb = *(const float4*)(cbias + head * 4);
  const float o0 = hv.x + cb.x + acc0 * inv;
  const float o1 = hv.y + cb.y + acc1 * inv;
  const float o2 = hv.z + cb.z + acc2 * inv;
  const float o3 = hv.w + cb.w + acc3 * inv;
  float pj[NUM_CLASS];
  const float* wr0 = wp + (head * 4 + 0) * NUM_CLASS;
  const float* wr1 = wp + (head * 4 + 1) * NUM_CLASS;
  const float* wr2 = wp + (head * 4 + 2) * NUM_CLASS;
  const float* wr3 = wp + (head * 4 + 3) * NUM_CLASS;
  #pragma unroll
  for (int j = 0; j < NUM_CLASS; ++j)
    pj[j] = o0 * wr0[j] + o1 * wr1[j] + o2 * wr2[j] + o3 * wr3[j];
  #pragma unroll
  for (int m = 1; m <= 4; m <<= 1) {
    #pragma unroll
    for (int j = 0; j < NUM_CLASS; ++j) pj[j] += __shfl_xor(pj[j], m, 64);
  }
  if (lane == 0) {
    #pragma unroll
    for (int j = 0; j < NUM_CLASS; ++j)
      out[(size_t)node * NUM_CLASS + j] = pj[j] + bp[j];
  }
}

// ---------------------------------------------------------------------------
extern "C" void kernel_launch(void* const* d_in, const int* in_sizes, int n_in,
                              void* d_out, int out_size, void* d_ws, size_t ws_size,
                              hipStream_t stream) {
  const float* x       = (const float*)d_in[0];
  const int*   ei      = (const int*)d_in[1];
  const float* w_proj  = (const float*)d_in[2];
  const float* b_proj  = (const float*)d_in[3];
  const float* w_l     = (const float*)d_in[4];
  const float* b_l     = (const float*)d_in[5];
  const float* w_r     = (const float*)d_in[6];
  const float* b_r     = (const float*)d_in[7];
  const float* att     = (const float*)d_in[8];
  const float* cbias   = (const float*)d_in[9];
  const float* w_pred  = (const float*)d_in[10];
  const float* b_pred  = (const float*)d_in[11];

  const int* e_src = ei;
  const int* e_dst = ei + N_EDGES;

  char* wsp = (char*)d_ws;
  size_t off = 0;
  auto take = [&](size_t bytes) -> void* {
    void* p = wsp + off;
    off += (bytes + 255) & ~(size_t)255;
    return p;
  };
  float*  h0    = (float*)take((size_t)N_NODES * DIM * 4);
  float*  h1    = (float*)take((size_t)N_NODES * DIM * 4);
  __bf16* xlbA  = (__bf16*)take((size_t)N_NODES * DIM * 2);
  float*  xrA   = (float*)take((size_t)N_NODES * DIM * 4);
  __bf16* xlbB  = (__bf16*)take((size_t)N_NODES * DIM * 2);
  float*  xrB   = (float*)take((size_t)N_NODES * DIM * 4);
  int*    offs  = (int*)take((size_t)(N_NODES + 1) * 4);
  int*    cnt   = (int*)take((size_t)N_NODES * 4);
  int*    bsum  = (int*)take((size_t)NB_SCAN * 4);
  int*    srcs  = (int*)take((size_t)N_EDGES * 4);
  int*    rank  = (int*)take((size_t)N_EDGES * 4);
  bf16x8* wfrag = (bf16x8*)take((size_t)KTILES * 2 * 64 * 16);

  // 1. init: zero cnt + wfrag pack
  init_kernel<<<(N_NODES + 255) / 256, 256, 0, stream>>>(w_proj, wfrag, cnt);
  // 2. proj + degree count + rank capture
  proj_count_kernel<<<PROJ_BLOCKS, 256, 0, stream>>>(
      x, wfrag, b_proj, h0, e_dst, cnt, rank);
  // 3-4. scan
  scan_local_kernel<<<NB_SCAN, 1024, 0, stream>>>(cnt, offs, bsum);
  scan_add_kernel<<<(N_NODES + 255) / 256, 256, 0, stream>>>(offs, bsum);
  // 5. scatter (atomic-free) || lgemm layer 0
  scatter_lgemm_kernel<<<25000, 256, 0, stream>>>(
      e_src, e_dst, offs, rank, srcs,
      h0, w_l, b_l, w_r, b_r, xlbA, xrA);
  // 6. gat layer 0 -> h1, + fused lgemm layer 1 -> xlbB/xrB
  gat_lgemm_kernel<<<N_NODES / 4, 256, 0, stream>>>(
      h0, xlbA, xrA, att, cbias, offs, srcs, h1,
      w_l + DIM * DIM, b_l + DIM, w_r + DIM * DIM, b_r + DIM, xlbB, xrB);
  // 7. gat layer 1 + pred -> d_out
  gat_edge_pred_kernel<<<N_NODES / 4, 256, 0, stream>>>(
      h1, xlbB, xrB, att + HEADS * OUT_C, cbias + DIM, offs, srcs,
      w_pred, b_pred, (float*)d_out);
}